// Round 5
// baseline (5057.137 us; speedup 1.0000x reference)
//
#include <hip/hip_runtime.h>
#include <hip/hip_bf16.h>

// Sizes
#define BB 16
#define NSEQ 20
#define HEADS 8
#define DH 96
#define DIM 768
#define FF 3072
#define KMEM 32768
#define NCH3 16
#define CH3 2048
#define CAP3 48

typedef __attribute__((ext_vector_type(8))) short short8v;
typedef __attribute__((ext_vector_type(4))) float f32x4;

__device__ __forceinline__ short f2b(float x) {
    __hip_bfloat16 h = __float2bfloat16(x);
    return *reinterpret_cast<short*>(&h);
}

// ---------------------------------------------------------------- MFMA GEMM (waves on N; used for M=16 init and wkv)
__global__ __launch_bounds__(256) void gemm_mfma(const float* __restrict__ A, const float* __restrict__ B,
    const float* __restrict__ bias, const float* __restrict__ resid, float* __restrict__ C,
    int M, int N, int K, int lda, int ldc, float scale, int act)
{
    int tid = threadIdx.x;
    int w = tid >> 6, lane = tid & 63;
    int m0 = blockIdx.y * 16;
    int n0 = blockIdx.x * 128 + w * 32;
    int row = lane & 15;
    int kg  = lane >> 4;
    const float* arow = A + (size_t)(m0 + row) * lda;
    int c0 = n0 + row;
    int c1 = n0 + 16 + row;
    int c0c = min(c0, N - 1);
    int c1c = min(c1, N - 1);
    f32x4 acc0 = {0.f, 0.f, 0.f, 0.f};
    f32x4 acc1 = {0.f, 0.f, 0.f, 0.f};

    for (int k0 = 0; k0 < K; k0 += 32) {
        int kb = k0 + kg * 8;
        float av[8];
        *(float4*)(av)     = *(const float4*)(arow + kb);
        *(float4*)(av + 4) = *(const float4*)(arow + kb + 4);
        const float* bp0 = B + c0c;
        const float* bp1 = B + c1c;
        float bv0[8], bv1[8];
#pragma unroll
        for (int j = 0; j < 8; j++) {
            bv0[j] = bp0[(size_t)(kb + j) * N];
            bv1[j] = bp1[(size_t)(kb + j) * N];
        }
        short8v af, b0f, b1f;
#pragma unroll
        for (int j = 0; j < 8; j++) {
            af[j]  = f2b(av[j]);
            b0f[j] = f2b(bv0[j]);
            b1f[j] = f2b(bv1[j]);
        }
        acc0 = __builtin_amdgcn_mfma_f32_16x16x32_bf16(af, b0f, acc0, 0, 0, 0);
        acc1 = __builtin_amdgcn_mfma_f32_16x16x32_bf16(af, b1f, acc1, 0, 0, 0);
    }

#pragma unroll
    for (int r = 0; r < 4; r++) {
        int rw = m0 + kg * 4 + r;
        if (c0 < N) {
            float v = acc0[r] * scale;
            if (bias) v += bias[c0];
            if (act) {
                float xx = v;
                float tt = 0.7978845608028654f * (xx + 0.044715f * xx * xx * xx);
                v = 0.5f * xx * (1.0f + tanhf(tt));
            }
            if (resid) v += resid[(size_t)rw * ldc + c0];
            C[(size_t)rw * ldc + c0] = v;
        }
        if (c1 < N) {
            float v = acc1[r] * scale;
            if (bias) v += bias[c1];
            if (act) {
                float xx = v;
                float tt = 0.7978845608028654f * (xx + 0.044715f * xx * xx * xx);
                v = 0.5f * xx * (1.0f + tanhf(tt));
            }
            if (resid) v += resid[(size_t)rw * ldc + c1];
            C[(size_t)rw * ldc + c1] = v;
        }
    }
}

// ---------------------------------------------------------------- MFMA GEMM (waves on M; 64 rows x 32 cols per block)
// Cuts B re-read redundancy from M/16 to M/64. M % 64 == 0, N % 32 == 0.
__global__ __launch_bounds__(256) void gemm_mfma_m4(const float* __restrict__ A, const float* __restrict__ B,
    const float* __restrict__ bias, const float* __restrict__ resid, float* __restrict__ C,
    int M, int N, int K, int lda, int ldc, float scale, int act)
{
    int tid = threadIdx.x;
    int w = tid >> 6, lane = tid & 63;
    int m0 = blockIdx.y * 64 + w * 16;
    int n0 = blockIdx.x * 32;
    int row = lane & 15;
    int kg  = lane >> 4;
    const float* arow = A + (size_t)(m0 + row) * lda;
    int c0 = n0 + row;
    int c1 = n0 + 16 + row;
    f32x4 acc0 = {0.f, 0.f, 0.f, 0.f};
    f32x4 acc1 = {0.f, 0.f, 0.f, 0.f};

    for (int k0 = 0; k0 < K; k0 += 32) {
        int kb = k0 + kg * 8;
        float av[8];
        *(float4*)(av)     = *(const float4*)(arow + kb);
        *(float4*)(av + 4) = *(const float4*)(arow + kb + 4);
        const float* bp0 = B + c0;
        const float* bp1 = B + c1;
        float bv0[8], bv1[8];
#pragma unroll
        for (int j = 0; j < 8; j++) {
            bv0[j] = bp0[(size_t)(kb + j) * N];
            bv1[j] = bp1[(size_t)(kb + j) * N];
        }
        short8v af, b0f, b1f;
#pragma unroll
        for (int j = 0; j < 8; j++) {
            af[j]  = f2b(av[j]);
            b0f[j] = f2b(bv0[j]);
            b1f[j] = f2b(bv1[j]);
        }
        acc0 = __builtin_amdgcn_mfma_f32_16x16x32_bf16(af, b0f, acc0, 0, 0, 0);
        acc1 = __builtin_amdgcn_mfma_f32_16x16x32_bf16(af, b1f, acc1, 0, 0, 0);
    }

#pragma unroll
    for (int r = 0; r < 4; r++) {
        int rw = m0 + kg * 4 + r;
        {
            float v = acc0[r] * scale;
            if (bias) v += bias[c0];
            if (act) {
                float xx = v;
                float tt = 0.7978845608028654f * (xx + 0.044715f * xx * xx * xx);
                v = 0.5f * xx * (1.0f + tanhf(tt));
            }
            if (resid) v += resid[(size_t)rw * ldc + c0];
            C[(size_t)rw * ldc + c0] = v;
        }
        {
            float v = acc1[r] * scale;
            if (bias) v += bias[c1];
            if (act) {
                float xx = v;
                float tt = 0.7978845608028654f * (xx + 0.044715f * xx * xx * xx);
                v = 0.5f * xx * (1.0f + tanhf(tt));
            }
            if (resid) v += resid[(size_t)rw * ldc + c1];
            C[(size_t)rw * ldc + c1] = v;
        }
    }
}

// ---------------------------------------------------------------- LayerNorm
__global__ __launch_bounds__(256) void ln_k(const float* __restrict__ x, const float* __restrict__ g,
    const float* __restrict__ bb, float* __restrict__ y)
{
    int row = blockIdx.x;
    const float* xr = x + (size_t)row * DIM;
    int tid = threadIdx.x;
    float v0 = xr[tid], v1 = xr[tid + 256], v2 = xr[tid + 512];
    __shared__ float red[4];
    float s = v0 + v1 + v2;
    for (int off = 32; off; off >>= 1) s += __shfl_down(s, off);
    if ((tid & 63) == 0) red[tid >> 6] = s;
    __syncthreads();
    float mean = (red[0] + red[1] + red[2] + red[3]) * (1.f / 768.f);
    __syncthreads();
    float d0 = v0 - mean, d1 = v1 - mean, d2 = v2 - mean;
    s = d0 * d0 + d1 * d1 + d2 * d2;
    for (int off = 32; off; off >>= 1) s += __shfl_down(s, off);
    if ((tid & 63) == 0) red[tid >> 6] = s;
    __syncthreads();
    float var = (red[0] + red[1] + red[2] + red[3]) * (1.f / 768.f);
    float rs = rsqrtf(var + 1e-5f);
    float* yr = y + (size_t)row * DIM;
    yr[tid]       = d0 * rs * g[tid]       + bb[tid];
    yr[tid + 256] = d1 * rs * g[tid + 256] + bb[tid + 256];
    yr[tid + 512] = d2 * rs * g[tid + 512] + bb[tid + 512];
}

// Final LN over rows i>=10, f32 output (16,10,768)
__global__ __launch_bounds__(256) void lnf_k(const float* __restrict__ x, const float* __restrict__ g,
    const float* __restrict__ bb, float* __restrict__ out)
{
    int blk = blockIdx.x;
    int b = blk / 10, ii = blk - b * 10;
    int row = b * NSEQ + 10 + ii;
    const float* xr = x + (size_t)row * DIM;
    int tid = threadIdx.x;
    float v0 = xr[tid], v1 = xr[tid + 256], v2 = xr[tid + 512];
    __shared__ float red[4];
    float s = v0 + v1 + v2;
    for (int off = 32; off; off >>= 1) s += __shfl_down(s, off);
    if ((tid & 63) == 0) red[tid >> 6] = s;
    __syncthreads();
    float mean = (red[0] + red[1] + red[2] + red[3]) * (1.f / 768.f);
    __syncthreads();
    float d0 = v0 - mean, d1 = v1 - mean, d2 = v2 - mean;
    s = d0 * d0 + d1 * d1 + d2 * d2;
    for (int off = 32; off; off >>= 1) s += __shfl_down(s, off);
    if ((tid & 63) == 0) red[tid >> 6] = s;
    __syncthreads();
    float var = (red[0] + red[1] + red[2] + red[3]) * (1.f / 768.f);
    float rs = rsqrtf(var + 1e-5f);
    float* orow = out + ((size_t)(b * 10 + ii)) * DIM;
    orow[tid]       = d0 * rs * g[tid]       + bb[tid];
    orow[tid + 256] = d1 * rs * g[tid + 256] + bb[tid + 256];
    orow[tid + 512] = d2 * rs * g[tid + 512] + bb[tid + 512];
}

// ---------------------------------------------------------------- prefix rows
__global__ __launch_bounds__(256) void prefix_k(const float* __restrict__ p, float* __restrict__ t)
{
    int idx = blockIdx.x * 256 + threadIdx.x;
    if (idx < BB * 7680) {
        int b = idx / 7680;
        int r = idx - b * 7680;
        t[(size_t)b * (NSEQ * DIM) + 7680 + r] = p[r];
    }
}

// ---------------------------------------------------------------- local attention
__global__ __launch_bounds__(256) void lattn_k(const float* __restrict__ q, const float* __restrict__ kv,
    float* __restrict__ ao)
{
    int b = blockIdx.x, h = blockIdx.y;
    __shared__ float sims[NSEQ][NSEQ];
    __shared__ float probs[NSEQ][NSEQ];
    const float* qb = q + (size_t)b * NSEQ * DIM + h * DH;
    const float* kb = kv + (size_t)b * NSEQ * 192;
    int tid = threadIdx.x;
    for (int p = tid; p < NSEQ * NSEQ; p += 256) {
        int i = p / NSEQ, j = p - i * NSEQ;
        float s;
        if (j > i) s = -1.0e9f;
        else {
            s = 0.f;
            for (int d = 0; d < DH; d++) s = fmaf(qb[(size_t)i * DIM + d], kb[j * 192 + d], s);
        }
        sims[i][j] = s;
    }
    __syncthreads();
    if (tid < NSEQ) {
        int i = tid;
        float m = -1e30f;
        for (int j = 0; j < NSEQ; j++) m = fmaxf(m, sims[i][j]);
        float sum = 0.f;
        for (int j = 0; j < NSEQ; j++) { float e = expf(sims[i][j] - m); probs[i][j] = e; sum += e; }
        float inv = 1.f / sum;
        for (int j = 0; j < NSEQ; j++) probs[i][j] *= inv;
    }
    __syncthreads();
    for (int p = tid; p < NSEQ * DH; p += 256) {
        int i = p / DH, d = p - i * DH;
        float o = 0.f;
        for (int j = 0; j <= i; j++) o = fmaf(probs[i][j], kb[j * 192 + 96 + d], o);
        ao[((size_t)b * NSEQ + i) * DIM + h * DH + d] = o;
    }
}

// ---------------------------------------------------------------- top-k helpers
__device__ __forceinline__ bool tk_better(float va, int ia, float vb, int ib) {
    return (va > vb) || (va == vb && ia < ib);
}

__device__ __forceinline__ void lds_fence() {
    asm volatile("s_waitcnt lgkmcnt(0)" ::: "memory");
    __builtin_amdgcn_sched_barrier(0);
}

// Exact top-32 of buf[0..cnt) by (value desc, idx asc). Bitonic-128 in regs.
__device__ void topk32(float* bv, int* bi, int cnt, int lane,
                       float& ov, int& oi, float& thr_out) {
    lds_fence();
    float v0 = (lane < cnt)      ? bv[lane]      : -3.0e38f;
    int   i0 = (lane < cnt)      ? bi[lane]      : 0x7fffffff;
    float v1 = (lane + 64 < cnt) ? bv[lane + 64] : -3.0e38f;
    int   i1 = (lane + 64 < cnt) ? bi[lane + 64] : 0x7fffffff;
    lds_fence();
#pragma unroll
    for (int k = 2; k <= 128; k <<= 1) {
#pragma unroll
        for (int j = 64; j >= 1; j >>= 1) {
            if (j >= k) continue;
            if (j == 64) {
                bool asc = ((lane & k) == 0);
                bool b01 = tk_better(v0, i0, v1, i1);
                if (b01 != asc) { float tv = v0; int ti = i0; v0 = v1; i0 = i1; v1 = tv; i1 = ti; }
            } else {
                {
                    float pv = __shfl_xor(v0, j); int pi = __shfl_xor(i0, j);
                    bool asc = ((lane & k) == 0);
                    bool first = ((lane & j) == 0);
                    bool mb = tk_better(v0, i0, pv, pi);
                    bool keep = first ? (mb == asc) : (mb != asc);
                    if (!keep) { v0 = pv; i0 = pi; }
                }
                {
                    float pv = __shfl_xor(v1, j); int pi = __shfl_xor(i1, j);
                    bool asc = (((lane + 64) & k) == 0);
                    bool first = ((lane & j) == 0);
                    bool mb = tk_better(v1, i1, pv, pi);
                    bool keep = first ? (mb == asc) : (mb != asc);
                    if (!keep) { v1 = pv; i1 = pi; }
                }
            }
        }
    }
    if (lane < 32) { bv[lane] = v0; bi[lane] = i0; }
    lds_fence();
    ov = v0; oi = i0;
    thr_out = __shfl(v0, 31);
}

// ---------------------------------------------------------------- mem top-k v3 (head-dedup)
// Block = (chunk c, batch b). 512 thr = 8 waves; wave = head. All heads share
// one streaming pass over the chunk's keys (regs); q staged once in LDS.
// Dot-product arithmetic identical to v2 (quarter-split + shfl_xor 1,2).
__global__ __launch_bounds__(512, 2) void memtopk_k(const float* __restrict__ q, const float* __restrict__ memk,
    float* __restrict__ tkv, int* __restrict__ tki)
{
    extern __shared__ float smem[];
    float* q_s      = smem;                          // [8 heads][20 rows][96] = 15360 f32
    float* bufv_all = smem + NSEQ * DIM;             // [8][20][CAP3] f32
    int*   bufi_all = (int*)(smem + NSEQ * DIM + HEADS * NSEQ * CAP3);

    int c = blockIdx.x, b = blockIdx.y;
    int tid = threadIdx.x;
    int lane = tid & 63;
    int h = tid >> 6;                 // wave = head
    int qt = lane & 3;                // dim quarter
    int kk = lane >> 2;               // key within 16-group

    // stage q for batch b: (row i, dim d) -> q_s[(d/96)*20 + i][d%96]
    const float4* qg = (const float4*)(q + (size_t)b * NSEQ * DIM);
    float4* q_s4 = (float4*)q_s;
    for (int idx = tid; idx < NSEQ * DIM / 4; idx += 512) {
        int i = idx / (DIM / 4);
        int rem = idx - i * (DIM / 4);
        int hh = rem / 24;
        int dd4 = rem - hh * 24;
        q_s4[(hh * NSEQ + i) * 24 + dd4] = qg[idx];
    }
    __syncthreads();

    float* bufv = bufv_all + (size_t)h * NSEQ * CAP3;
    int*   bufi = bufi_all + (size_t)h * NSEQ * CAP3;
    const float* qrow_base = q_s + (size_t)h * NSEQ * DH + qt * 24;

    float thr[NSEQ]; int cnt[NSEQ];
#pragma unroll
    for (int r = 0; r < NSEQ; r++) { thr[r] = -3.0e38f; cnt[r] = 0; }

    const float* kb = memk + (size_t)b * KMEM * DH;
    int k0 = c * CH3;

    for (int p = 0; p < CH3 / 16; p++) {
        int key = k0 + p * 16 + kk;
        const float4* kp = (const float4*)(kb + (size_t)key * DH + qt * 24);
        float4 kr[6];
#pragma unroll
        for (int i = 0; i < 6; i++) kr[i] = kp[i];
#pragma unroll
        for (int r = 0; r < NSEQ; r++) {
            const float4* qp = (const float4*)(qrow_base + r * DH);
            float a = 0.f;
#pragma unroll
            for (int i = 0; i < 6; i++) {
                float4 qv = qp[i];
                a = fmaf(qv.x, kr[i].x, a);
                a = fmaf(qv.y, kr[i].y, a);
                a = fmaf(qv.z, kr[i].z, a);
                a = fmaf(qv.w, kr[i].w, a);
            }
            a += __shfl_xor(a, 1);
            a += __shfl_xor(a, 2);
            bool cand = (qt == 0) && (a > thr[r]);
            unsigned long long mask = __ballot(cand);
            if (mask) {
                int n = __popcll(mask);
                if (cnt[r] + n > CAP3) {
                    float dv; int di;
                    topk32(bufv + r * CAP3, bufi + r * CAP3, cnt[r], lane, dv, di, thr[r]);
                    cnt[r] = 32;
                }
                int pos = cnt[r] + __popcll(mask & ((1ull << lane) - 1ull));
                if (cand) { bufv[r * CAP3 + pos] = a; bufi[r * CAP3 + pos] = key; }
                cnt[r] += n;
            }
        }
    }
#pragma unroll
    for (int r = 0; r < NSEQ; r++) {
        float ov; int oi; float dthr;
        topk32(bufv + r * CAP3, bufi + r * CAP3, cnt[r], lane, ov, oi, dthr);
        if (lane < 32) {
            size_t base = ((((size_t)b * HEADS + h) * NSEQ + r) * NCH3 + c) * 32;
            tkv[base + lane] = ov;
            tki[base + lane] = oi;
        }
    }
}

// ---------------------------------------------------------------- mem attention merge (per (i,h,b))
// Merges NCH3*32 = 512 candidates -> exact top-32 -> softmax with local -> output.
__global__ __launch_bounds__(64) void memattn_k(const float* __restrict__ q, const float* __restrict__ kv,
    const float* __restrict__ memv, const float* __restrict__ tkv, const int* __restrict__ tki,
    float* __restrict__ ao)
{
    int i = blockIdx.x, h = blockIdx.y, b = blockIdx.z;
    __shared__ float cv[NCH3 * 32];
    __shared__ int   ci[NCH3 * 32];
    __shared__ float selv[32];
    __shared__ int   seli[32];
    __shared__ float ls[NSEQ];
    __shared__ float probs[52];
    int tid = threadIdx.x;
    size_t base = (((size_t)b * HEADS + h) * NSEQ + i) * (NCH3 * 32);
#pragma unroll
    for (int s = 0; s < NCH3 * 32 / 64; s++) {
        cv[tid + 64 * s] = tkv[base + tid + 64 * s];
        ci[tid + 64 * s] = tki[base + tid + 64 * s];
    }
    const float* qr = q + ((size_t)b * NSEQ + i) * DIM + h * DH;
    const float* kvb = kv + (size_t)b * NSEQ * 192;
    if (tid <= i) {
        float s = 0.f;
        for (int d = 0; d < DH; d++) s = fmaf(qr[d], kvb[tid * 192 + d], s);
        ls[tid] = s;
    }
    __syncthreads();
    for (int r = 0; r < 32; r++) {
        float bv = -3.0e38f; int bidx = 0x7fffffff; int bs = 0;
#pragma unroll
        for (int s = 0; s < NCH3 * 32 / 64; s++) {
            float v = cv[tid + 64 * s]; int ix = ci[tid + 64 * s];
            if (tk_better(v, ix, bv, bidx)) { bv = v; bidx = ix; bs = tid + 64 * s; }
        }
        for (int off = 32; off; off >>= 1) {
            float ovv = __shfl_down(bv, off);
            int oii = __shfl_down(bidx, off);
            int oss = __shfl_down(bs, off);
            if (tk_better(ovv, oii, bv, bidx)) { bv = ovv; bidx = oii; bs = oss; }
        }
        if (tid == 0) { selv[r] = bv; seli[r] = bidx; cv[bs] = -3.0e38f; }
        __syncthreads();
    }
    if (tid == 0) {
        float m = -1e30f;
        for (int r = 0; r < 32; r++) m = fmaxf(m, selv[r]);
        for (int j = 0; j <= i; j++) m = fmaxf(m, ls[j]);
        float sum = 0.f;
        for (int r = 0; r < 32; r++) { float e = expf(selv[r] - m); probs[r] = e; sum += e; }
        for (int j = 0; j <= i; j++) { float e = expf(ls[j] - m); probs[32 + j] = e; sum += e; }
        float inv = 1.f / sum;
        for (int r = 0; r < 32 + i + 1; r++) probs[r] *= inv;
    }
    __syncthreads();
    const float* mvb = memv + (size_t)b * KMEM * DH;
    for (int d = tid; d < DH; d += 64) {
        float o = 0.f;
        for (int r = 0; r < 32; r++) o = fmaf(probs[r], mvb[(size_t)seli[r] * DH + d], o);
        for (int j = 0; j <= i; j++) o = fmaf(probs[32 + j], kvb[j * 192 + 96 + d], o);
        ao[((size_t)b * NSEQ + i) * DIM + h * DH + d] = o;
    }
}

// ---------------------------------------------------------------- host
extern "C" void kernel_launch(void* const* d_in, const int* in_sizes, int n_in,
                              void* d_out, int out_size, void* d_ws, size_t ws_size,
                              hipStream_t stream) {
    const float* x            = (const float*)d_in[0];
    const float* linear_w     = (const float*)d_in[1];
    const float* linear_b     = (const float*)d_in[2];
    const float* prefix_const = (const float*)d_in[3];
    const float* ln1_g        = (const float*)d_in[4];
    const float* ln1_b        = (const float*)d_in[5];
    const float* wq           = (const float*)d_in[6];
    const float* wkv          = (const float*)d_in[7];
    const float* wo           = (const float*)d_in[8];
    const float* ln2_g        = (const float*)d_in[9];
    const float* ln2_b        = (const float*)d_in[10];
    const float* w1           = (const float*)d_in[11];
    const float* b1           = (const float*)d_in[12];
    const float* w2           = (const float*)d_in[13];
    const float* b2           = (const float*)d_in[14];
    const float* lnf_g        = (const float*)d_in[15];
    const float* lnf_b        = (const float*)d_in[16];
    const float* mem_k        = (const float*)d_in[17];
    const float* mem_v        = (const float*)d_in[18];

    float* ws = (float*)d_ws;
    float* t   = ws;                   // 320*768
    float* y   = ws + 245760;
    float* qb  = ws + 491520;
    float* kvb = ws + 737280;          // 320*192
    float* ao  = ws + 798720;
    float* h1  = ws + 1044480;         // 320*3072 -> ends 2027520
    float* tkv = ws + 2027520;         // 16*8*20*16*32 = 1310720
    int*   tki = (int*)(ws + 3338240); // 1310720 -> ends 4648960
    float* out = (float*)d_out;

    const float qscale = 0.10206207261596577f; // 96^-0.5
    const int smem_topk = (NSEQ * DIM + 2 * HEADS * NSEQ * CAP3) * 4; // 122880 B

    gemm_mfma<<<dim3(60, 1), 256, 0, stream>>>(x, linear_w, linear_b, nullptr, t,
                                               16, 7680, 640, 640, 15360, 1.f, 0);
    prefix_k<<<dim3(480), 256, 0, stream>>>(prefix_const, t);

    for (int l = 0; l < 8; l++) {
        ln_k<<<320, 256, 0, stream>>>(t, ln1_g + (size_t)l * DIM, ln1_b + (size_t)l * DIM, y);
        gemm_mfma_m4<<<dim3(24, 5), 256, 0, stream>>>(y, wq + (size_t)l * DIM * DIM, nullptr, nullptr, qb,
                                                      320, 768, 768, 768, 768, qscale, 0);
        gemm_mfma<<<dim3(2, 20), 256, 0, stream>>>(y, wkv + (size_t)l * DIM * 192, nullptr, nullptr, kvb,
                                                   320, 192, 768, 768, 192, 1.f, 0);
        if (l == 4 || l == 5) {
            memtopk_k<<<dim3(NCH3, BB), 512, smem_topk, stream>>>(qb, mem_k, tkv, tki);
            memattn_k<<<dim3(NSEQ, HEADS, BB), 64, 0, stream>>>(qb, kvb, mem_v, tkv, tki, ao);
        } else {
            lattn_k<<<dim3(BB, HEADS), 256, 0, stream>>>(qb, kvb, ao);
        }
        gemm_mfma_m4<<<dim3(24, 5), 256, 0, stream>>>(ao, wo + (size_t)l * DIM * DIM, nullptr, t, t,
                                                      320, 768, 768, 768, 768, 1.f, 0);
        ln_k<<<320, 256, 0, stream>>>(t, ln2_g + (size_t)l * DIM, ln2_b + (size_t)l * DIM, y);
        gemm_mfma_m4<<<dim3(96, 5), 256, 0, stream>>>(y, w1 + (size_t)l * DIM * FF, b1 + (size_t)l * FF, nullptr, h1,
                                                      320, 3072, 768, 768, 3072, 1.f, 1);
        gemm_mfma_m4<<<dim3(24, 5), 256, 0, stream>>>(h1, w2 + (size_t)l * FF * DIM, b2 + (size_t)l * DIM, t, t,
                                                      320, 768, 3072, 3072, 768, 1.f, 0);
    }
    lnf_k<<<160, 256, 0, stream>>>(t, lnf_g, lnf_b, out);
}

// Round 6
// 2456.545 us; speedup vs baseline: 2.0586x; 2.0586x over previous
//
#include <hip/hip_runtime.h>
#include <hip/hip_bf16.h>

// Sizes
#define BB 16
#define NSEQ 20
#define HEADS 8
#define DH 96
#define DIM 768
#define FF 3072
#define KMEM 32768
#define NCHUNK 4
#define CHUNK 8192
#define CAP 128

typedef __attribute__((ext_vector_type(8))) short short8v;
typedef __attribute__((ext_vector_type(4))) float f32x4;

__device__ __forceinline__ short f2b(float x) {
    __hip_bfloat16 h = __float2bfloat16(x);
    return *reinterpret_cast<short*>(&h);
}

// ---------------------------------------------------------------- MFMA GEMM
// C[m][n] = act(scale * sum_k A[m][k]*B[k][n] + bias[n]) + resid[m][n]
// f32 in/out, bf16 MFMA compute. Block = 256 thr = 4 waves; wave w owns a
// 16x32 tile at cols n0 + w*32; grid = (ceil(N/128), M/16). M % 16 == 0.
__global__ __launch_bounds__(256) void gemm_mfma(const float* __restrict__ A, const float* __restrict__ B,
    const float* __restrict__ bias, const float* __restrict__ resid, float* __restrict__ C,
    int M, int N, int K, int lda, int ldc, float scale, int act)
{
    int tid = threadIdx.x;
    int w = tid >> 6, lane = tid & 63;
    int m0 = blockIdx.y * 16;
    int n0 = blockIdx.x * 128 + w * 32;
    int row = lane & 15;
    int kg  = lane >> 4;
    const float* arow = A + (size_t)(m0 + row) * lda;
    int c0 = n0 + row;
    int c1 = n0 + 16 + row;
    int c0c = min(c0, N - 1);
    int c1c = min(c1, N - 1);
    f32x4 acc0 = {0.f, 0.f, 0.f, 0.f};
    f32x4 acc1 = {0.f, 0.f, 0.f, 0.f};

    for (int k0 = 0; k0 < K; k0 += 32) {
        int kb = k0 + kg * 8;
        float av[8];
        *(float4*)(av)     = *(const float4*)(arow + kb);
        *(float4*)(av + 4) = *(const float4*)(arow + kb + 4);
        const float* bp0 = B + c0c;
        const float* bp1 = B + c1c;
        float bv0[8], bv1[8];
#pragma unroll
        for (int j = 0; j < 8; j++) {
            bv0[j] = bp0[(size_t)(kb + j) * N];
            bv1[j] = bp1[(size_t)(kb + j) * N];
        }
        short8v af, b0f, b1f;
#pragma unroll
        for (int j = 0; j < 8; j++) {
            af[j]  = f2b(av[j]);
            b0f[j] = f2b(bv0[j]);
            b1f[j] = f2b(bv1[j]);
        }
        acc0 = __builtin_amdgcn_mfma_f32_16x16x32_bf16(af, b0f, acc0, 0, 0, 0);
        acc1 = __builtin_amdgcn_mfma_f32_16x16x32_bf16(af, b1f, acc1, 0, 0, 0);
    }

#pragma unroll
    for (int r = 0; r < 4; r++) {
        int rw = m0 + kg * 4 + r;
        if (c0 < N) {
            float v = acc0[r] * scale;
            if (bias) v += bias[c0];
            if (act) {
                float xx = v;
                float tt = 0.7978845608028654f * (xx + 0.044715f * xx * xx * xx);
                v = 0.5f * xx * (1.0f + tanhf(tt));
            }
            if (resid) v += resid[(size_t)rw * ldc + c0];
            C[(size_t)rw * ldc + c0] = v;
        }
        if (c1 < N) {
            float v = acc1[r] * scale;
            if (bias) v += bias[c1];
            if (act) {
                float xx = v;
                float tt = 0.7978845608028654f * (xx + 0.044715f * xx * xx * xx);
                v = 0.5f * xx * (1.0f + tanhf(tt));
            }
            if (resid) v += resid[(size_t)rw * ldc + c1];
            C[(size_t)rw * ldc + c1] = v;
        }
    }
}

// ---------------------------------------------------------------- LayerNorm
__global__ __launch_bounds__(256) void ln_k(const float* __restrict__ x, const float* __restrict__ g,
    const float* __restrict__ bb, float* __restrict__ y)
{
    int row = blockIdx.x;
    const float* xr = x + (size_t)row * DIM;
    int tid = threadIdx.x;
    float v0 = xr[tid], v1 = xr[tid + 256], v2 = xr[tid + 512];
    __shared__ float red[4];
    float s = v0 + v1 + v2;
    for (int off = 32; off; off >>= 1) s += __shfl_down(s, off);
    if ((tid & 63) == 0) red[tid >> 6] = s;
    __syncthreads();
    float mean = (red[0] + red[1] + red[2] + red[3]) * (1.f / 768.f);
    __syncthreads();
    float d0 = v0 - mean, d1 = v1 - mean, d2 = v2 - mean;
    s = d0 * d0 + d1 * d1 + d2 * d2;
    for (int off = 32; off; off >>= 1) s += __shfl_down(s, off);
    if ((tid & 63) == 0) red[tid >> 6] = s;
    __syncthreads();
    float var = (red[0] + red[1] + red[2] + red[3]) * (1.f / 768.f);
    float rs = rsqrtf(var + 1e-5f);
    float* yr = y + (size_t)row * DIM;
    yr[tid]       = d0 * rs * g[tid]       + bb[tid];
    yr[tid + 256] = d1 * rs * g[tid + 256] + bb[tid + 256];
    yr[tid + 512] = d2 * rs * g[tid + 512] + bb[tid + 512];
}

// Final LN over rows i>=10, f32 output (16,10,768)
__global__ __launch_bounds__(256) void lnf_k(const float* __restrict__ x, const float* __restrict__ g,
    const float* __restrict__ bb, float* __restrict__ out)
{
    int blk = blockIdx.x;
    int b = blk / 10, ii = blk - b * 10;
    int row = b * NSEQ + 10 + ii;
    const float* xr = x + (size_t)row * DIM;
    int tid = threadIdx.x;
    float v0 = xr[tid], v1 = xr[tid + 256], v2 = xr[tid + 512];
    __shared__ float red[4];
    float s = v0 + v1 + v2;
    for (int off = 32; off; off >>= 1) s += __shfl_down(s, off);
    if ((tid & 63) == 0) red[tid >> 6] = s;
    __syncthreads();
    float mean = (red[0] + red[1] + red[2] + red[3]) * (1.f / 768.f);
    __syncthreads();
    float d0 = v0 - mean, d1 = v1 - mean, d2 = v2 - mean;
    s = d0 * d0 + d1 * d1 + d2 * d2;
    for (int off = 32; off; off >>= 1) s += __shfl_down(s, off);
    if ((tid & 63) == 0) red[tid >> 6] = s;
    __syncthreads();
    float var = (red[0] + red[1] + red[2] + red[3]) * (1.f / 768.f);
    float rs = rsqrtf(var + 1e-5f);
    float* orow = out + ((size_t)(b * 10 + ii)) * DIM;
    orow[tid]       = d0 * rs * g[tid]       + bb[tid];
    orow[tid + 256] = d1 * rs * g[tid + 256] + bb[tid + 256];
    orow[tid + 512] = d2 * rs * g[tid + 512] + bb[tid + 512];
}

// ---------------------------------------------------------------- prefix rows
__global__ __launch_bounds__(256) void prefix_k(const float* __restrict__ p, float* __restrict__ t)
{
    int idx = blockIdx.x * 256 + threadIdx.x;
    if (idx < BB * 7680) {
        int b = idx / 7680;
        int r = idx - b * 7680;
        t[(size_t)b * (NSEQ * DIM) + 7680 + r] = p[r];
    }
}

// ---------------------------------------------------------------- local attention
__global__ __launch_bounds__(256) void lattn_k(const float* __restrict__ q, const float* __restrict__ kv,
    float* __restrict__ ao)
{
    int b = blockIdx.x, h = blockIdx.y;
    __shared__ float sims[NSEQ][NSEQ];
    __shared__ float probs[NSEQ][NSEQ];
    const float* qb = q + (size_t)b * NSEQ * DIM + h * DH;
    const float* kb = kv + (size_t)b * NSEQ * 192;
    int tid = threadIdx.x;
    for (int p = tid; p < NSEQ * NSEQ; p += 256) {
        int i = p / NSEQ, j = p - i * NSEQ;
        float s;
        if (j > i) s = -1.0e9f;
        else {
            s = 0.f;
            for (int d = 0; d < DH; d++) s = fmaf(qb[(size_t)i * DIM + d], kb[j * 192 + d], s);
        }
        sims[i][j] = s;
    }
    __syncthreads();
    if (tid < NSEQ) {
        int i = tid;
        float m = -1e30f;
        for (int j = 0; j < NSEQ; j++) m = fmaxf(m, sims[i][j]);
        float sum = 0.f;
        for (int j = 0; j < NSEQ; j++) { float e = expf(sims[i][j] - m); probs[i][j] = e; sum += e; }
        float inv = 1.f / sum;
        for (int j = 0; j < NSEQ; j++) probs[i][j] *= inv;
    }
    __syncthreads();
    for (int p = tid; p < NSEQ * DH; p += 256) {
        int i = p / DH, d = p - i * DH;
        float o = 0.f;
        for (int j = 0; j <= i; j++) o = fmaf(probs[i][j], kb[j * 192 + 96 + d], o);
        ao[((size_t)b * NSEQ + i) * DIM + h * DH + d] = o;
    }
}

// ---------------------------------------------------------------- top-k helpers
__device__ __forceinline__ bool tk_better(float va, int ia, float vb, int ib) {
    return (va > vb) || (va == vb && ia < ib);
}

__device__ __forceinline__ void lds_fence() {
    asm volatile("s_waitcnt lgkmcnt(0)" ::: "memory");
    __builtin_amdgcn_sched_barrier(0);
}

// Exact top-32 of buf[0..cnt) by (value desc, idx asc). Bitonic-128 in regs.
__device__ void topk32(float* bv, int* bi, int cnt, int lane,
                       float& ov, int& oi, float& thr_out) {
    lds_fence();
    float v0 = (lane < cnt)      ? bv[lane]      : -3.0e38f;
    int   i0 = (lane < cnt)      ? bi[lane]      : 0x7fffffff;
    float v1 = (lane + 64 < cnt) ? bv[lane + 64] : -3.0e38f;
    int   i1 = (lane + 64 < cnt) ? bi[lane + 64] : 0x7fffffff;
    lds_fence();
#pragma unroll
    for (int k = 2; k <= 128; k <<= 1) {
#pragma unroll
        for (int j = 64; j >= 1; j >>= 1) {
            if (j >= k) continue;
            if (j == 64) {
                bool asc = ((lane & k) == 0);
                bool b01 = tk_better(v0, i0, v1, i1);
                if (b01 != asc) { float tv = v0; int ti = i0; v0 = v1; i0 = i1; v1 = tv; i1 = ti; }
            } else {
                {
                    float pv = __shfl_xor(v0, j); int pi = __shfl_xor(i0, j);
                    bool asc = ((lane & k) == 0);
                    bool first = ((lane & j) == 0);
                    bool mb = tk_better(v0, i0, pv, pi);
                    bool keep = first ? (mb == asc) : (mb != asc);
                    if (!keep) { v0 = pv; i0 = pi; }
                }
                {
                    float pv = __shfl_xor(v1, j); int pi = __shfl_xor(i1, j);
                    bool asc = (((lane + 64) & k) == 0);
                    bool first = ((lane & j) == 0);
                    bool mb = tk_better(v1, i1, pv, pi);
                    bool keep = first ? (mb == asc) : (mb != asc);
                    if (!keep) { v1 = pv; i1 = pi; }
                }
            }
        }
    }
    if (lane < 32) { bv[lane] = v0; bi[lane] = i0; }
    lds_fence();
    ov = v0; oi = i0;
    thr_out = __shfl(v0, 31);
}

// One 16-key pass: dot (quarter-split), 4-lane reduce, threshold/ballot append.
__device__ __forceinline__ void tk_pass(const float4 kr[6], const float4 qreg[5][6],
    float thrR[5], int cntR[5], float (*bufv)[CAP], int (*bufi)[CAP],
    int r0, int lane, int qt, int key)
{
    float a[5];
#pragma unroll
    for (int rr = 0; rr < 5; rr++) a[rr] = 0.f;
#pragma unroll
    for (int i = 0; i < 6; i++) {
        float4 kv = kr[i];
#pragma unroll
        for (int rr = 0; rr < 5; rr++) {
            float4 qv = qreg[rr][i];
            a[rr] = fmaf(qv.x, kv.x, a[rr]);
            a[rr] = fmaf(qv.y, kv.y, a[rr]);
            a[rr] = fmaf(qv.z, kv.z, a[rr]);
            a[rr] = fmaf(qv.w, kv.w, a[rr]);
        }
    }
#pragma unroll
    for (int rr = 0; rr < 5; rr++) {
        a[rr] += __shfl_xor(a[rr], 1);
        a[rr] += __shfl_xor(a[rr], 2);
    }
#pragma unroll
    for (int rr = 0; rr < 5; rr++) {
        bool cand = (qt == 0) && (a[rr] >= thrR[rr]);
        unsigned long long mask = __ballot(cand);
        int n = __popcll(mask);
        if (n) {
            int r = r0 + rr;
            if (cntR[rr] + n > CAP) {
                float dv; int di;
                topk32(&bufv[r][0], &bufi[r][0], cntR[rr], lane, dv, di, thrR[rr]);
                cntR[rr] = 32;
            }
            int pos = cntR[rr] + __popcll(mask & ((1ull << lane) - 1ull));
            if (cand) { bufv[r][pos] = a[rr]; bufi[r][pos] = key; }
            cntR[rr] += n;
        }
    }
}

// ---------------------------------------------------------------- mem top-k v4
// Block (c,h,b), 256 thr = 4 waves; wave w owns rows 5w..5w+4. Q held in regs
// (launch_bounds(256,2) gives the allocator room); k double-buffered in regs.
__global__ __launch_bounds__(256, 2) void memtopk_k(const float* __restrict__ q, const float* __restrict__ memk,
    float* __restrict__ tkv, int* __restrict__ tki)
{
    __shared__ float bufv[NSEQ][CAP];
    __shared__ int   bufi[NSEQ][CAP];
    int c = blockIdx.x, h = blockIdx.y, b = blockIdx.z;
    int tid = threadIdx.x;
    int lane = tid & 63;
    int w = tid >> 6;
    int r0 = w * 5;
    int qt = lane & 3;
    int kk = lane >> 2;

    float4 qreg[5][6];
#pragma unroll
    for (int rr = 0; rr < 5; rr++) {
        const float4* qrow = (const float4*)(q + ((size_t)(b * NSEQ + r0 + rr)) * DIM + h * DH + qt * 24);
#pragma unroll
        for (int i = 0; i < 6; i++) qreg[rr][i] = qrow[i];
    }

    float thrR[5]; int cntR[5];
#pragma unroll
    for (int rr = 0; rr < 5; rr++) { thrR[rr] = -3.0e38f; cntR[rr] = 0; }

    const float* kbase = memk + (size_t)b * KMEM * DH;
    int k0 = c * CHUNK;

    float4 ka[6], kb2[6];
    {
        const float4* kp = (const float4*)(kbase + (size_t)(k0 + kk) * DH + qt * 24);
#pragma unroll
        for (int i = 0; i < 6; i++) ka[i] = kp[i];
    }
    for (int p = 0; p < CHUNK / 16; p += 2) {
        int key0 = k0 + p * 16 + kk;
        {
            const float4* kp = (const float4*)(kbase + (size_t)(key0 + 16) * DH + qt * 24);
#pragma unroll
            for (int i = 0; i < 6; i++) kb2[i] = kp[i];
        }
        tk_pass(ka, qreg, thrR, cntR, bufv, bufi, r0, lane, qt, key0);
        if (p + 2 < CHUNK / 16) {
            const float4* kp = (const float4*)(kbase + (size_t)(key0 + 32) * DH + qt * 24);
#pragma unroll
            for (int i = 0; i < 6; i++) ka[i] = kp[i];
        }
        tk_pass(kb2, qreg, thrR, cntR, bufv, bufi, r0, lane, qt, key0 + 16);
    }
#pragma unroll
    for (int rr = 0; rr < 5; rr++) {
        int r = r0 + rr;
        float ov; int oi; float dthr;
        topk32(&bufv[r][0], &bufi[r][0], cntR[rr], lane, ov, oi, dthr);
        if (lane < 32) {
            size_t base = ((((size_t)b * HEADS + h) * NSEQ + r) * NCHUNK + c) * 32;
            tkv[base + lane] = ov;
            tki[base + lane] = oi;
        }
    }
}

// ---------------------------------------------------------------- mem attention merge (per (i,h,b))
// Merges NCHUNK*32 = 128 candidates -> exact top-32 -> softmax with local -> output.
__global__ __launch_bounds__(64) void memattn_k(const float* __restrict__ q, const float* __restrict__ kv,
    const float* __restrict__ memv, const float* __restrict__ tkv, const int* __restrict__ tki,
    float* __restrict__ ao)
{
    int i = blockIdx.x, h = blockIdx.y, b = blockIdx.z;
    __shared__ float cv[NCHUNK * 32];
    __shared__ int   ci[NCHUNK * 32];
    __shared__ float selv[32];
    __shared__ int   seli[32];
    __shared__ float ls[NSEQ];
    __shared__ float probs[52];
    int tid = threadIdx.x;
    size_t base = (((size_t)b * HEADS + h) * NSEQ + i) * (NCHUNK * 32);
#pragma unroll
    for (int s = 0; s < NCHUNK * 32 / 64; s++) {
        cv[tid + 64 * s] = tkv[base + tid + 64 * s];
        ci[tid + 64 * s] = tki[base + tid + 64 * s];
    }
    const float* qr = q + ((size_t)b * NSEQ + i) * DIM + h * DH;
    const float* kvb = kv + (size_t)b * NSEQ * 192;
    if (tid <= i) {
        float s = 0.f;
        for (int d = 0; d < DH; d++) s = fmaf(qr[d], kvb[tid * 192 + d], s);
        ls[tid] = s;
    }
    __syncthreads();
    for (int r = 0; r < 32; r++) {
        float bv = -3.0e38f; int bidx = 0x7fffffff; int bs = 0;
#pragma unroll
        for (int s = 0; s < NCHUNK * 32 / 64; s++) {
            float v = cv[tid + 64 * s]; int ix = ci[tid + 64 * s];
            if (tk_better(v, ix, bv, bidx)) { bv = v; bidx = ix; bs = tid + 64 * s; }
        }
        for (int off = 32; off; off >>= 1) {
            float ovv = __shfl_down(bv, off);
            int oii = __shfl_down(bidx, off);
            int oss = __shfl_down(bs, off);
            if (tk_better(ovv, oii, bv, bidx)) { bv = ovv; bidx = oii; bs = oss; }
        }
        if (tid == 0) { selv[r] = bv; seli[r] = bidx; cv[bs] = -3.0e38f; }
        __syncthreads();
    }
    if (tid == 0) {
        float m = -1e30f;
        for (int r = 0; r < 32; r++) m = fmaxf(m, selv[r]);
        for (int j = 0; j <= i; j++) m = fmaxf(m, ls[j]);
        float sum = 0.f;
        for (int r = 0; r < 32; r++) { float e = expf(selv[r] - m); probs[r] = e; sum += e; }
        for (int j = 0; j <= i; j++) { float e = expf(ls[j] - m); probs[32 + j] = e; sum += e; }
        float inv = 1.f / sum;
        for (int r = 0; r < 32 + i + 1; r++) probs[r] *= inv;
    }
    __syncthreads();
    const float* mvb = memv + (size_t)b * KMEM * DH;
    for (int d = tid; d < DH; d += 64) {
        float o = 0.f;
        for (int r = 0; r < 32; r++) o = fmaf(probs[r], mvb[(size_t)seli[r] * DH + d], o);
        for (int j = 0; j <= i; j++) o = fmaf(probs[32 + j], kvb[j * 192 + 96 + d], o);
        ao[((size_t)b * NSEQ + i) * DIM + h * DH + d] = o;
    }
}

// ---------------------------------------------------------------- host
extern "C" void kernel_launch(void* const* d_in, const int* in_sizes, int n_in,
                              void* d_out, int out_size, void* d_ws, size_t ws_size,
                              hipStream_t stream) {
    const float* x            = (const float*)d_in[0];
    const float* linear_w     = (const float*)d_in[1];
    const float* linear_b     = (const float*)d_in[2];
    const float* prefix_const = (const float*)d_in[3];
    const float* ln1_g        = (const float*)d_in[4];
    const float* ln1_b        = (const float*)d_in[5];
    const float* wq           = (const float*)d_in[6];
    const float* wkv          = (const float*)d_in[7];
    const float* wo           = (const float*)d_in[8];
    const float* ln2_g        = (const float*)d_in[9];
    const float* ln2_b        = (const float*)d_in[10];
    const float* w1           = (const float*)d_in[11];
    const float* b1           = (const float*)d_in[12];
    const float* w2           = (const float*)d_in[13];
    const float* b2           = (const float*)d_in[14];
    const float* lnf_g        = (const float*)d_in[15];
    const float* lnf_b        = (const float*)d_in[16];
    const float* mem_k        = (const float*)d_in[17];
    const float* mem_v        = (const float*)d_in[18];

    float* ws = (float*)d_ws;
    float* t   = ws;                   // 320*768
    float* y   = ws + 245760;
    float* qb  = ws + 491520;
    float* kvb = ws + 737280;          // 320*192
    float* ao  = ws + 798720;
    float* h1  = ws + 1044480;         // 320*3072 -> ends 2027520
    float* tkv = ws + 2027520;         // 16*8*20*4*32 = 327680
    int*   tki = (int*)(ws + 2355200); // 327680
    float* out = (float*)d_out;

    const float qscale = 0.10206207261596577f; // 96^-0.5

    gemm_mfma<<<dim3(60, 1), 256, 0, stream>>>(x, linear_w, linear_b, nullptr, t,
                                               16, 7680, 640, 640, 15360, 1.f, 0);
    prefix_k<<<dim3(480), 256, 0, stream>>>(prefix_const, t);

    for (int l = 0; l < 8; l++) {
        ln_k<<<320, 256, 0, stream>>>(t, ln1_g + (size_t)l * DIM, ln1_b + (size_t)l * DIM, y);
        gemm_mfma<<<dim3(6, 20), 256, 0, stream>>>(y, wq + (size_t)l * DIM * DIM, nullptr, nullptr, qb,
                                                   320, 768, 768, 768, 768, qscale, 0);
        gemm_mfma<<<dim3(2, 20), 256, 0, stream>>>(y, wkv + (size_t)l * DIM * 192, nullptr, nullptr, kvb,
                                                   320, 192, 768, 768, 192, 1.f, 0);
        if (l == 4 || l == 5) {
            memtopk_k<<<dim3(NCHUNK, HEADS, BB), 256, 0, stream>>>(qb, mem_k, tkv, tki);
            memattn_k<<<dim3(NSEQ, HEADS, BB), 64, 0, stream>>>(qb, kvb, mem_v, tkv, tki, ao);
        } else {
            lattn_k<<<dim3(BB, HEADS), 256, 0, stream>>>(qb, kvb, ao);
        }
        gemm_mfma<<<dim3(6, 20), 256, 0, stream>>>(ao, wo + (size_t)l * DIM * DIM, nullptr, t, t,
                                                   320, 768, 768, 768, 768, 1.f, 0);
        ln_k<<<320, 256, 0, stream>>>(t, ln2_g + (size_t)l * DIM, ln2_b + (size_t)l * DIM, y);
        gemm_mfma<<<dim3(24, 20), 256, 0, stream>>>(y, w1 + (size_t)l * DIM * FF, b1 + (size_t)l * FF, nullptr, h1,
                                                    320, 3072, 768, 768, 3072, 1.f, 1);
        gemm_mfma<<<dim3(6, 20), 256, 0, stream>>>(h1, w2 + (size_t)l * FF * DIM, b2 + (size_t)l * DIM, t, t,
                                                   320, 768, 3072, 3072, 768, 1.f, 0);
    }
    lnf_k<<<160, 256, 0, stream>>>(t, lnf_g, lnf_b, out);
}

// Round 7
// 2297.605 us; speedup vs baseline: 2.2010x; 1.0692x over previous
//
#include <hip/hip_runtime.h>
#include <hip/hip_bf16.h>

// Sizes
#define BB 16
#define NSEQ 20
#define HEADS 8
#define DH 96
#define DIM 768
#define FF 3072
#define KMEM 32768
#define NCHUNK 8
#define CHUNK 4096
#define CAP 128

typedef unsigned short u16;
typedef __attribute__((ext_vector_type(8))) short short8v;
typedef __attribute__((ext_vector_type(4))) float f32x4;

__device__ __forceinline__ u16 f2bu(float x) {
    __hip_bfloat16 h = __float2bfloat16(x);
    return *reinterpret_cast<u16*>(&h);
}

// ---------------------------------------------------------------- weight conversion
// flat f32 -> bf16
__global__ __launch_bounds__(256) void conv_k(const float* __restrict__ src, u16* __restrict__ dst, int n)
{
    int i = blockIdx.x * 256 + threadIdx.x;
    if (i < n) dst[i] = f2bu(src[i]);
}

// transpose-convert one 32x32 tile: src[K][N] f32 -> dst[N][K] bf16 (dims % 32 == 0)
__device__ __forceinline__ void tconv_tile(const float* __restrict__ src, u16* __restrict__ dst,
                                           int K, int N, int kt, int nt, int tx, int ty)
{
    __shared__ float tile[32][33];
    int k0 = kt * 32, n0 = nt * 32;
#pragma unroll
    for (int i = 0; i < 4; i++)
        tile[ty + 8 * i][tx] = src[(size_t)(k0 + ty + 8 * i) * N + n0 + tx];
    __syncthreads();
#pragma unroll
    for (int i = 0; i < 4; i++)
        dst[(size_t)(n0 + ty + 8 * i) * K + k0 + tx] = f2bu(tile[tx][ty + 8 * i]);
}

__global__ __launch_bounds__(256) void tconv_k(const float* __restrict__ src, u16* __restrict__ dst, int K, int N)
{
    int tilesN = N >> 5;
    tconv_tile(src, dst, K, N, blockIdx.x / tilesN, blockIdx.x % tilesN,
               threadIdx.x & 31, threadIdx.x >> 5);
}

// all 5 weights of one layer in a single launch
__global__ __launch_bounds__(256) void wconv5_k(const float* __restrict__ wq, const float* __restrict__ wkv,
    const float* __restrict__ wo, const float* __restrict__ w1, const float* __restrict__ w2,
    u16* __restrict__ wt)
{
    int bx = blockIdx.x;
    int tx = threadIdx.x & 31, ty = threadIdx.x >> 5;
    if (bx < 576)       tconv_tile(wq,  wt + 0,       768, 768,  bx / 24,          bx % 24,          tx, ty);
    else if (bx < 720)  tconv_tile(wkv, wt + 589824,  768, 192,  (bx - 576) / 6,   (bx - 576) % 6,   tx, ty);
    else if (bx < 1296) tconv_tile(wo,  wt + 737280,  768, 768,  (bx - 720) / 24,  (bx - 720) % 24,  tx, ty);
    else if (bx < 3600) tconv_tile(w1,  wt + 1327104, 768, 3072, (bx - 1296) / 96, (bx - 1296) % 96, tx, ty);
    else                tconv_tile(w2,  wt + 3686400, 3072, 768, (bx - 3600) / 24, (bx - 3600) % 24, tx, ty);
}

// ---------------------------------------------------------------- MFMA GEMM, bf16 A[M][K] x Bt[N][K]
__device__ __forceinline__ void storeC(float* C, size_t idx, float v) { C[idx] = v; }
__device__ __forceinline__ void storeC(u16* C, size_t idx, float v)   { C[idx] = f2bu(v); }

template <typename CT>
__global__ __launch_bounds__(256) void gemm_bt(const u16* __restrict__ A, const u16* __restrict__ Bt,
    const float* __restrict__ bias, const float* __restrict__ resid, CT* __restrict__ C,
    int M, int N, int K, int lda, int ldc, float scale, int act)
{
    int tid = threadIdx.x;
    int w = tid >> 6, lane = tid & 63;
    int m0 = blockIdx.y * 16;
    int n0 = blockIdx.x * 128 + w * 32;
    int row = lane & 15;
    int kg  = lane >> 4;
    const u16* arow = A + (size_t)(m0 + row) * lda + kg * 8;
    int c0 = n0 + row;
    int c1 = n0 + 16 + row;
    const u16* bt0 = Bt + (size_t)min(c0, N - 1) * K + kg * 8;
    const u16* bt1 = Bt + (size_t)min(c1, N - 1) * K + kg * 8;
    f32x4 acc0 = {0.f, 0.f, 0.f, 0.f};
    f32x4 acc1 = {0.f, 0.f, 0.f, 0.f};
#pragma unroll 2
    for (int k0 = 0; k0 < K; k0 += 32) {
        short8v af = *(const short8v*)(arow + k0);
        short8v b0 = *(const short8v*)(bt0 + k0);
        short8v b1 = *(const short8v*)(bt1 + k0);
        acc0 = __builtin_amdgcn_mfma_f32_16x16x32_bf16(af, b0, acc0, 0, 0, 0);
        acc1 = __builtin_amdgcn_mfma_f32_16x16x32_bf16(af, b1, acc1, 0, 0, 0);
    }
#pragma unroll
    for (int r = 0; r < 4; r++) {
        int rw = m0 + kg * 4 + r;
        if (c0 < N) {
            float v = acc0[r] * scale;
            if (bias) v += bias[c0];
            if (act) {
                float xx = v;
                float tt = 0.7978845608028654f * (xx + 0.044715f * xx * xx * xx);
                v = 0.5f * xx * (1.0f + tanhf(tt));
            }
            if (resid) v += resid[(size_t)rw * ldc + c0];
            storeC(C, (size_t)rw * ldc + c0, v);
        }
        if (c1 < N) {
            float v = acc1[r] * scale;
            if (bias) v += bias[c1];
            if (act) {
                float xx = v;
                float tt = 0.7978845608028654f * (xx + 0.044715f * xx * xx * xx);
                v = 0.5f * xx * (1.0f + tanhf(tt));
            }
            if (resid) v += resid[(size_t)rw * ldc + c1];
            storeC(C, (size_t)rw * ldc + c1, v);
        }
    }
}

// ---------------------------------------------------------------- LayerNorm (bf16 out for GEMM A-operand)
__global__ __launch_bounds__(256) void ln_k(const float* __restrict__ x, const float* __restrict__ g,
    const float* __restrict__ bb, u16* __restrict__ y)
{
    int row = blockIdx.x;
    const float* xr = x + (size_t)row * DIM;
    int tid = threadIdx.x;
    float v0 = xr[tid], v1 = xr[tid + 256], v2 = xr[tid + 512];
    __shared__ float red[4];
    float s = v0 + v1 + v2;
    for (int off = 32; off; off >>= 1) s += __shfl_down(s, off);
    if ((tid & 63) == 0) red[tid >> 6] = s;
    __syncthreads();
    float mean = (red[0] + red[1] + red[2] + red[3]) * (1.f / 768.f);
    __syncthreads();
    float d0 = v0 - mean, d1 = v1 - mean, d2 = v2 - mean;
    s = d0 * d0 + d1 * d1 + d2 * d2;
    for (int off = 32; off; off >>= 1) s += __shfl_down(s, off);
    if ((tid & 63) == 0) red[tid >> 6] = s;
    __syncthreads();
    float var = (red[0] + red[1] + red[2] + red[3]) * (1.f / 768.f);
    float rs = rsqrtf(var + 1e-5f);
    u16* yr = y + (size_t)row * DIM;
    yr[tid]       = f2bu(d0 * rs * g[tid]       + bb[tid]);
    yr[tid + 256] = f2bu(d1 * rs * g[tid + 256] + bb[tid + 256]);
    yr[tid + 512] = f2bu(d2 * rs * g[tid + 512] + bb[tid + 512]);
}

// Final LN over rows i>=10, f32 output (16,10,768)
__global__ __launch_bounds__(256) void lnf_k(const float* __restrict__ x, const float* __restrict__ g,
    const float* __restrict__ bb, float* __restrict__ out)
{
    int blk = blockIdx.x;
    int b = blk / 10, ii = blk - b * 10;
    int row = b * NSEQ + 10 + ii;
    const float* xr = x + (size_t)row * DIM;
    int tid = threadIdx.x;
    float v0 = xr[tid], v1 = xr[tid + 256], v2 = xr[tid + 512];
    __shared__ float red[4];
    float s = v0 + v1 + v2;
    for (int off = 32; off; off >>= 1) s += __shfl_down(s, off);
    if ((tid & 63) == 0) red[tid >> 6] = s;
    __syncthreads();
    float mean = (red[0] + red[1] + red[2] + red[3]) * (1.f / 768.f);
    __syncthreads();
    float d0 = v0 - mean, d1 = v1 - mean, d2 = v2 - mean;
    s = d0 * d0 + d1 * d1 + d2 * d2;
    for (int off = 32; off; off >>= 1) s += __shfl_down(s, off);
    if ((tid & 63) == 0) red[tid >> 6] = s;
    __syncthreads();
    float var = (red[0] + red[1] + red[2] + red[3]) * (1.f / 768.f);
    float rs = rsqrtf(var + 1e-5f);
    float* orow = out + ((size_t)(b * 10 + ii)) * DIM;
    orow[tid]       = d0 * rs * g[tid]       + bb[tid];
    orow[tid + 256] = d1 * rs * g[tid + 256] + bb[tid + 256];
    orow[tid + 512] = d2 * rs * g[tid + 512] + bb[tid + 512];
}

// ---------------------------------------------------------------- prefix rows
__global__ __launch_bounds__(256) void prefix_k(const float* __restrict__ p, float* __restrict__ t)
{
    int idx = blockIdx.x * 256 + threadIdx.x;
    if (idx < BB * 7680) {
        int b = idx / 7680;
        int r = idx - b * 7680;
        t[(size_t)b * (NSEQ * DIM) + 7680 + r] = p[r];
    }
}

// ---------------------------------------------------------------- local attention (ao bf16)
__global__ __launch_bounds__(256) void lattn_k(const float* __restrict__ q, const float* __restrict__ kv,
    u16* __restrict__ ao)
{
    int b = blockIdx.x, h = blockIdx.y;
    __shared__ float sims[NSEQ][NSEQ];
    __shared__ float probs[NSEQ][NSEQ];
    const float* qb = q + (size_t)b * NSEQ * DIM + h * DH;
    const float* kb = kv + (size_t)b * NSEQ * 192;
    int tid = threadIdx.x;
    for (int p = tid; p < NSEQ * NSEQ; p += 256) {
        int i = p / NSEQ, j = p - i * NSEQ;
        float s;
        if (j > i) s = -1.0e9f;
        else {
            s = 0.f;
            for (int d = 0; d < DH; d++) s = fmaf(qb[(size_t)i * DIM + d], kb[j * 192 + d], s);
        }
        sims[i][j] = s;
    }
    __syncthreads();
    if (tid < NSEQ) {
        int i = tid;
        float m = -1e30f;
        for (int j = 0; j < NSEQ; j++) m = fmaxf(m, sims[i][j]);
        float sum = 0.f;
        for (int j = 0; j < NSEQ; j++) { float e = expf(sims[i][j] - m); probs[i][j] = e; sum += e; }
        float inv = 1.f / sum;
        for (int j = 0; j < NSEQ; j++) probs[i][j] *= inv;
    }
    __syncthreads();
    for (int p = tid; p < NSEQ * DH; p += 256) {
        int i = p / DH, d = p - i * DH;
        float o = 0.f;
        for (int j = 0; j <= i; j++) o = fmaf(probs[i][j], kb[j * 192 + 96 + d], o);
        ao[((size_t)b * NSEQ + i) * DIM + h * DH + d] = f2bu(o);
    }
}

// ---------------------------------------------------------------- top-k helpers
__device__ __forceinline__ bool tk_better(float va, int ia, float vb, int ib) {
    return (va > vb) || (va == vb && ia < ib);
}

__device__ __forceinline__ void lds_fence() {
    asm volatile("s_waitcnt lgkmcnt(0)" ::: "memory");
    __builtin_amdgcn_sched_barrier(0);
}

// Exact top-32 of buf[0..cnt) by (value desc, idx asc). Bitonic-128 in regs.
__device__ void topk32(float* bv, int* bi, int cnt, int lane,
                       float& ov, int& oi, float& thr_out) {
    lds_fence();
    float v0 = (lane < cnt)      ? bv[lane]      : -3.0e38f;
    int   i0 = (lane < cnt)      ? bi[lane]      : 0x7fffffff;
    float v1 = (lane + 64 < cnt) ? bv[lane + 64] : -3.0e38f;
    int   i1 = (lane + 64 < cnt) ? bi[lane + 64] : 0x7fffffff;
    lds_fence();
#pragma unroll
    for (int k = 2; k <= 128; k <<= 1) {
#pragma unroll
        for (int j = 64; j >= 1; j >>= 1) {
            if (j >= k) continue;
            if (j == 64) {
                bool asc = ((lane & k) == 0);
                bool b01 = tk_better(v0, i0, v1, i1);
                if (b01 != asc) { float tv = v0; int ti = i0; v0 = v1; i0 = i1; v1 = tv; i1 = ti; }
            } else {
                {
                    float pv = __shfl_xor(v0, j); int pi = __shfl_xor(i0, j);
                    bool asc = ((lane & k) == 0);
                    bool first = ((lane & j) == 0);
                    bool mb = tk_better(v0, i0, pv, pi);
                    bool keep = first ? (mb == asc) : (mb != asc);
                    if (!keep) { v0 = pv; i0 = pi; }
                }
                {
                    float pv = __shfl_xor(v1, j); int pi = __shfl_xor(i1, j);
                    bool asc = (((lane + 64) & k) == 0);
                    bool first = ((lane & j) == 0);
                    bool mb = tk_better(v1, i1, pv, pi);
                    bool keep = first ? (mb == asc) : (mb != asc);
                    if (!keep) { v1 = pv; i1 = pi; }
                }
            }
        }
    }
    if (lane < 32) { bv[lane] = v0; bi[lane] = i0; }
    lds_fence();
    ov = v0; oi = i0;
    thr_out = __shfl(v0, 31);
}

// One 16-key pass: dot (quarter-split), 4-lane reduce, threshold/ballot append.
__device__ __forceinline__ void tk_pass(const float4 kr[6], const float4 qreg[5][6],
    float thrR[5], int cntR[5], float (*bufv)[CAP], int (*bufi)[CAP],
    int r0, int lane, int qt, int key)
{
    float a[5];
#pragma unroll
    for (int rr = 0; rr < 5; rr++) a[rr] = 0.f;
#pragma unroll
    for (int i = 0; i < 6; i++) {
        float4 kv = kr[i];
#pragma unroll
        for (int rr = 0; rr < 5; rr++) {
            float4 qv = qreg[rr][i];
            a[rr] = fmaf(qv.x, kv.x, a[rr]);
            a[rr] = fmaf(qv.y, kv.y, a[rr]);
            a[rr] = fmaf(qv.z, kv.z, a[rr]);
            a[rr] = fmaf(qv.w, kv.w, a[rr]);
        }
    }
#pragma unroll
    for (int rr = 0; rr < 5; rr++) {
        a[rr] += __shfl_xor(a[rr], 1);
        a[rr] += __shfl_xor(a[rr], 2);
    }
#pragma unroll
    for (int rr = 0; rr < 5; rr++) {
        bool cand = (qt == 0) && (a[rr] >= thrR[rr]);
        unsigned long long mask = __ballot(cand);
        int n = __popcll(mask);
        if (n) {
            int r = r0 + rr;
            if (cntR[rr] + n > CAP) {
                float dv; int di;
                topk32(&bufv[r][0], &bufi[r][0], cntR[rr], lane, dv, di, thrR[rr]);
                cntR[rr] = 32;
            }
            int pos = cntR[rr] + __popcll(mask & ((1ull << lane) - 1ull));
            if (cand) { bufv[r][pos] = a[rr]; bufi[r][pos] = key; }
            cntR[rr] += n;
        }
    }
}

// ---------------------------------------------------------------- mem top-k
// Block (c,h,b), 256 thr = 4 waves; wave w owns rows 5w..5w+4. Q in regs,
// k double-buffered in regs. 1024 blocks -> 4 blocks/CU.
__global__ __launch_bounds__(256, 2) void memtopk_k(const float* __restrict__ q, const float* __restrict__ memk,
    float* __restrict__ tkv, int* __restrict__ tki)
{
    __shared__ float bufv[NSEQ][CAP];
    __shared__ int   bufi[NSEQ][CAP];
    int c = blockIdx.x, h = blockIdx.y, b = blockIdx.z;
    int tid = threadIdx.x;
    int lane = tid & 63;
    int w = tid >> 6;
    int r0 = w * 5;
    int qt = lane & 3;
    int kk = lane >> 2;

    float4 qreg[5][6];
#pragma unroll
    for (int rr = 0; rr < 5; rr++) {
        const float4* qrow = (const float4*)(q + ((size_t)(b * NSEQ + r0 + rr)) * DIM + h * DH + qt * 24);
#pragma unroll
        for (int i = 0; i < 6; i++) qreg[rr][i] = qrow[i];
    }

    float thrR[5]; int cntR[5];
#pragma unroll
    for (int rr = 0; rr < 5; rr++) { thrR[rr] = -3.0e38f; cntR[rr] = 0; }

    const float* kbase = memk + (size_t)b * KMEM * DH;
    int k0 = c * CHUNK;

    float4 ka[6], kb2[6];
    {
        const float4* kp = (const float4*)(kbase + (size_t)(k0 + kk) * DH + qt * 24);
#pragma unroll
        for (int i = 0; i < 6; i++) ka[i] = kp[i];
    }
    for (int p = 0; p < CHUNK / 16; p += 2) {
        int key0 = k0 + p * 16 + kk;
        {
            const float4* kp = (const float4*)(kbase + (size_t)(key0 + 16) * DH + qt * 24);
#pragma unroll
            for (int i = 0; i < 6; i++) kb2[i] = kp[i];
        }
        tk_pass(ka, qreg, thrR, cntR, bufv, bufi, r0, lane, qt, key0);
        if (p + 2 < CHUNK / 16) {
            const float4* kp = (const float4*)(kbase + (size_t)(key0 + 32) * DH + qt * 24);
#pragma unroll
            for (int i = 0; i < 6; i++) ka[i] = kp[i];
        }
        tk_pass(kb2, qreg, thrR, cntR, bufv, bufi, r0, lane, qt, key0 + 16);
    }
#pragma unroll
    for (int rr = 0; rr < 5; rr++) {
        int r = r0 + rr;
        float ov; int oi; float dthr;
        topk32(&bufv[r][0], &bufi[r][0], cntR[rr], lane, ov, oi, dthr);
        if (lane < 32) {
            size_t base = ((((size_t)b * HEADS + h) * NSEQ + r) * NCHUNK + c) * 32;
            tkv[base + lane] = ov;
            tki[base + lane] = oi;
        }
    }
}

// ---------------------------------------------------------------- mem attention merge (per (i,h,b))
// Merges NCHUNK*32 = 256 candidates -> exact top-32 -> softmax with local -> bf16 output.
__global__ __launch_bounds__(64) void memattn_k(const float* __restrict__ q, const float* __restrict__ kv,
    const float* __restrict__ memv, const float* __restrict__ tkv, const int* __restrict__ tki,
    u16* __restrict__ ao)
{
    int i = blockIdx.x, h = blockIdx.y, b = blockIdx.z;
    __shared__ float cv[NCHUNK * 32];
    __shared__ int   ci[NCHUNK * 32];
    __shared__ float selv[32];
    __shared__ int   seli[32];
    __shared__ float ls[NSEQ];
    __shared__ float probs[52];
    int tid = threadIdx.x;
    size_t base = (((size_t)b * HEADS + h) * NSEQ + i) * (NCHUNK * 32);
#pragma unroll
    for (int s = 0; s < NCHUNK * 32 / 64; s++) {
        cv[tid + 64 * s] = tkv[base + tid + 64 * s];
        ci[tid + 64 * s] = tki[base + tid + 64 * s];
    }
    const float* qr = q + ((size_t)b * NSEQ + i) * DIM + h * DH;
    const float* kvb = kv + (size_t)b * NSEQ * 192;
    if (tid <= i) {
        float s = 0.f;
        for (int d = 0; d < DH; d++) s = fmaf(qr[d], kvb[tid * 192 + d], s);
        ls[tid] = s;
    }
    __syncthreads();
    for (int r = 0; r < 32; r++) {
        float bv = -3.0e38f; int bidx = 0x7fffffff; int bs = 0;
#pragma unroll
        for (int s = 0; s < NCHUNK * 32 / 64; s++) {
            float v = cv[tid + 64 * s]; int ix = ci[tid + 64 * s];
            if (tk_better(v, ix, bv, bidx)) { bv = v; bidx = ix; bs = tid + 64 * s; }
        }
        for (int off = 32; off; off >>= 1) {
            float ovv = __shfl_down(bv, off);
            int oii = __shfl_down(bidx, off);
            int oss = __shfl_down(bs, off);
            if (tk_better(ovv, oii, bv, bidx)) { bv = ovv; bidx = oii; bs = oss; }
        }
        if (tid == 0) { selv[r] = bv; seli[r] = bidx; cv[bs] = -3.0e38f; }
        __syncthreads();
    }
    if (tid == 0) {
        float m = -1e30f;
        for (int r = 0; r < 32; r++) m = fmaxf(m, selv[r]);
        for (int j = 0; j <= i; j++) m = fmaxf(m, ls[j]);
        float sum = 0.f;
        for (int r = 0; r < 32; r++) { float e = expf(selv[r] - m); probs[r] = e; sum += e; }
        for (int j = 0; j <= i; j++) { float e = expf(ls[j] - m); probs[32 + j] = e; sum += e; }
        float inv = 1.f / sum;
        for (int r = 0; r < 32 + i + 1; r++) probs[r] *= inv;
    }
    __syncthreads();
    const float* mvb = memv + (size_t)b * KMEM * DH;
    for (int d = tid; d < DH; d += 64) {
        float o = 0.f;
        for (int r = 0; r < 32; r++) o = fmaf(probs[r], mvb[(size_t)seli[r] * DH + d], o);
        for (int j = 0; j <= i; j++) o = fmaf(probs[32 + j], kvb[j * 192 + 96 + d], o);
        ao[((size_t)b * NSEQ + i) * DIM + h * DH + d] = f2bu(o);
    }
}

// ---------------------------------------------------------------- host
extern "C" void kernel_launch(void* const* d_in, const int* in_sizes, int n_in,
                              void* d_out, int out_size, void* d_ws, size_t ws_size,
                              hipStream_t stream) {
    const float* x            = (const float*)d_in[0];
    const float* linear_w     = (const float*)d_in[1];
    const float* linear_b     = (const float*)d_in[2];
    const float* prefix_const = (const float*)d_in[3];
    const float* ln1_g        = (const float*)d_in[4];
    const float* ln1_b        = (const float*)d_in[5];
    const float* wq           = (const float*)d_in[6];
    const float* wkv          = (const float*)d_in[7];
    const float* wo           = (const float*)d_in[8];
    const float* ln2_g        = (const float*)d_in[9];
    const float* ln2_b        = (const float*)d_in[10];
    const float* w1           = (const float*)d_in[11];
    const float* b1           = (const float*)d_in[12];
    const float* w2           = (const float*)d_in[13];
    const float* b2           = (const float*)d_in[14];
    const float* lnf_g        = (const float*)d_in[15];
    const float* lnf_b        = (const float*)d_in[16];
    const float* mem_k        = (const float*)d_in[17];
    const float* mem_v        = (const float*)d_in[18];

    float* ws = (float*)d_ws;
    float* t    = ws;                     // 320*768 f32
    u16*   yb   = (u16*)(ws + 245760);    // 320*768 bf16
    float* qb   = ws + 491520;            // 320*768 f32
    float* kvb  = ws + 737280;            // 320*192 f32
    u16*   aob  = (u16*)(ws + 798720);    // 320*768 bf16
    u16*   h1b  = (u16*)(ws + 1044480);   // 320*3072 bf16
    float* tkv  = ws + 2027520;           // 16*8*20*8*32 = 655360
    int*   tki  = (int*)(ws + 2682880);   // 655360
    u16*   wt   = (u16*)(ws + 3338240);   // 6045696 shorts (layer weights / linear_wt)
    u16*   xb   = (u16*)(ws + 6361088);   // 10240 shorts
    float* out  = (float*)d_out;

    const float qscale = 0.10206207261596577f; // 96^-0.5
    // wt offsets (shorts)
    const size_t WQT = 0, WKVT = 589824, WOT = 737280, W1T = 1327104, W2T = 3686400;

    // x and linear_w -> bf16 (linear_w transposed), then initial GEMM
    conv_k<<<40, 256, 0, stream>>>(x, xb, 16 * 640);
    tconv_k<<<4800, 256, 0, stream>>>(linear_w, wt, 640, 7680);
    gemm_bt<float><<<dim3(60, 1), 256, 0, stream>>>(xb, wt, linear_b, nullptr, t,
                                                    16, 7680, 640, 640, 15360, 1.f, 0);
    prefix_k<<<dim3(480), 256, 0, stream>>>(prefix_const, t);

    for (int l = 0; l < 8; l++) {
        wconv5_k<<<5904, 256, 0, stream>>>(wq + (size_t)l * DIM * DIM, wkv + (size_t)l * DIM * 192,
                                           wo + (size_t)l * DIM * DIM, w1 + (size_t)l * DIM * FF,
                                           w2 + (size_t)l * FF * DIM, wt);
        ln_k<<<320, 256, 0, stream>>>(t, ln1_g + (size_t)l * DIM, ln1_b + (size_t)l * DIM, yb);
        gemm_bt<float><<<dim3(6, 20), 256, 0, stream>>>(yb, wt + WQT, nullptr, nullptr, qb,
                                                        320, 768, 768, 768, 768, qscale, 0);
        gemm_bt<float><<<dim3(2, 20), 256, 0, stream>>>(yb, wt + WKVT, nullptr, nullptr, kvb,
                                                        320, 192, 768, 768, 192, 1.f, 0);
        if (l == 4 || l == 5) {
            memtopk_k<<<dim3(NCHUNK, HEADS, BB), 256, 0, stream>>>(qb, mem_k, tkv, tki);
            memattn_k<<<dim3(NSEQ, HEADS, BB), 64, 0, stream>>>(qb, kvb, mem_v, tkv, tki, aob);
        } else {
            lattn_k<<<dim3(BB, HEADS), 256, 0, stream>>>(qb, kvb, aob);
        }
        gemm_bt<float><<<dim3(6, 20), 256, 0, stream>>>(aob, wt + WOT, nullptr, t, t,
                                                        320, 768, 768, 768, 768, 1.f, 0);
        ln_k<<<320, 256, 0, stream>>>(t, ln2_g + (size_t)l * DIM, ln2_b + (size_t)l * DIM, yb);
        gemm_bt<u16><<<dim3(24, 20), 256, 0, stream>>>(yb, wt + W1T, b1 + (size_t)l * FF, nullptr, h1b,
                                                       320, 3072, 768, 768, 3072, 1.f, 1);
        gemm_bt<float><<<dim3(6, 20), 256, 0, stream>>>(h1b, wt + W2T, b2 + (size_t)l * DIM, t, t,
                                                        320, 768, 3072, 3072, 768, 1.f, 0);
    }
    lnf_k<<<160, 256, 0, stream>>>(t, lnf_g, lnf_b, out);
}

// Round 8
// 2078.087 us; speedup vs baseline: 2.4336x; 1.1056x over previous
//
#include <hip/hip_runtime.h>
#include <hip/hip_bf16.h>

// Sizes
#define BB 16
#define NSEQ 20
#define HEADS 8
#define DH 96
#define DIM 768
#define FF 3072
#define KMEM 32768
#define NCHUNK 4
#define CHUNK 8192
#define CAP 128

typedef unsigned short u16;
typedef __attribute__((ext_vector_type(8))) short short8v;
typedef __attribute__((ext_vector_type(4))) float f32x4;

__device__ __forceinline__ u16 f2bu(float x) {
    __hip_bfloat16 h = __float2bfloat16(x);
    return *reinterpret_cast<u16*>(&h);
}

// ---------------------------------------------------------------- weight conversion
__global__ __launch_bounds__(256) void conv_k(const float* __restrict__ src, u16* __restrict__ dst, int n)
{
    int i = blockIdx.x * 256 + threadIdx.x;
    if (i < n) dst[i] = f2bu(src[i]);
}

// transpose-convert one 32x32 tile: src[K][N] f32 -> dst[N][K] bf16 (dims % 32 == 0)
__device__ __forceinline__ void tconv_tile(const float* __restrict__ src, u16* __restrict__ dst,
                                           int K, int N, int kt, int nt, int tx, int ty)
{
    __shared__ float tile[32][33];
    int k0 = kt * 32, n0 = nt * 32;
#pragma unroll
    for (int i = 0; i < 4; i++)
        tile[ty + 8 * i][tx] = src[(size_t)(k0 + ty + 8 * i) * N + n0 + tx];
    __syncthreads();
#pragma unroll
    for (int i = 0; i < 4; i++)
        dst[(size_t)(n0 + ty + 8 * i) * K + k0 + tx] = f2bu(tile[tx][ty + 8 * i]);
}

__global__ __launch_bounds__(256) void tconv_k(const float* __restrict__ src, u16* __restrict__ dst, int K, int N)
{
    int tilesN = N >> 5;
    tconv_tile(src, dst, K, N, blockIdx.x / tilesN, blockIdx.x % tilesN,
               threadIdx.x & 31, threadIdx.x >> 5);
}

// all 5 weights of layer (blockIdx.y) in one launch; wtStride in shorts (0 => per-layer reuse)
__global__ __launch_bounds__(256) void wconv5L_k(const float* __restrict__ wq, const float* __restrict__ wkv,
    const float* __restrict__ wo, const float* __restrict__ w1, const float* __restrict__ w2,
    u16* __restrict__ wt, size_t wtStride)
{
    int l = blockIdx.y;
    wq += (size_t)l * 589824;
    wkv += (size_t)l * 147456;
    wo += (size_t)l * 589824;
    w1 += (size_t)l * 2359296;
    w2 += (size_t)l * 2359296;
    wt += (size_t)l * wtStride;
    int bx = blockIdx.x;
    int tx = threadIdx.x & 31, ty = threadIdx.x >> 5;
    if (bx < 576)       tconv_tile(wq,  wt + 0,       768, 768,  bx / 24,          bx % 24,          tx, ty);
    else if (bx < 720)  tconv_tile(wkv, wt + 589824,  768, 192,  (bx - 576) / 6,   (bx - 576) % 6,   tx, ty);
    else if (bx < 1296) tconv_tile(wo,  wt + 737280,  768, 768,  (bx - 720) / 24,  (bx - 720) % 24,  tx, ty);
    else if (bx < 3600) tconv_tile(w1,  wt + 1327104, 768, 3072, (bx - 1296) / 96, (bx - 1296) % 96, tx, ty);
    else                tconv_tile(w2,  wt + 3686400, 3072, 768, (bx - 3600) / 24, (bx - 3600) % 24, tx, ty);
}

// ---------------------------------------------------------------- MFMA GEMM, bf16 A[M][K] x Bt[N][K]
__device__ __forceinline__ void storeC(float* C, size_t idx, float v) { C[idx] = v; }
__device__ __forceinline__ void storeC(u16* C, size_t idx, float v)   { C[idx] = f2bu(v); }

template <typename CT>
__global__ __launch_bounds__(256) void gemm_bt(const u16* __restrict__ A, const u16* __restrict__ Bt,
    const float* __restrict__ bias, const float* __restrict__ resid, CT* __restrict__ C,
    int M, int N, int K, int lda, int ldc, float scale, int act)
{
    int tid = threadIdx.x;
    int w = tid >> 6, lane = tid & 63;
    int m0 = blockIdx.y * 16;
    int n0 = blockIdx.x * 128 + w * 32;
    int row = lane & 15;
    int kg  = lane >> 4;
    const u16* arow = A + (size_t)(m0 + row) * lda + kg * 8;
    int c0 = n0 + row;
    int c1 = n0 + 16 + row;
    const u16* bt0 = Bt + (size_t)min(c0, N - 1) * K + kg * 8;
    const u16* bt1 = Bt + (size_t)min(c1, N - 1) * K + kg * 8;
    f32x4 acc0 = {0.f, 0.f, 0.f, 0.f};
    f32x4 acc1 = {0.f, 0.f, 0.f, 0.f};
#pragma unroll 2
    for (int k0 = 0; k0 < K; k0 += 32) {
        short8v af = *(const short8v*)(arow + k0);
        short8v b0 = *(const short8v*)(bt0 + k0);
        short8v b1 = *(const short8v*)(bt1 + k0);
        acc0 = __builtin_amdgcn_mfma_f32_16x16x32_bf16(af, b0, acc0, 0, 0, 0);
        acc1 = __builtin_amdgcn_mfma_f32_16x16x32_bf16(af, b1, acc1, 0, 0, 0);
    }
#pragma unroll
    for (int r = 0; r < 4; r++) {
        int rw = m0 + kg * 4 + r;
        if (c0 < N) {
            float v = acc0[r] * scale;
            if (bias) v += bias[c0];
            if (act) {
                float xx = v;
                float tt = 0.7978845608028654f * (xx + 0.044715f * xx * xx * xx);
                v = 0.5f * xx * (1.0f + tanhf(tt));
            }
            if (resid) v += resid[(size_t)rw * ldc + c0];
            storeC(C, (size_t)rw * ldc + c0, v);
        }
        if (c1 < N) {
            float v = acc1[r] * scale;
            if (bias) v += bias[c1];
            if (act) {
                float xx = v;
                float tt = 0.7978845608028654f * (xx + 0.044715f * xx * xx * xx);
                v = 0.5f * xx * (1.0f + tanhf(tt));
            }
            if (resid) v += resid[(size_t)rw * ldc + c1];
            storeC(C, (size_t)rw * ldc + c1, v);
        }
    }
}

// Fused q+kv projection: Bt = [wq^T ; wkv^T] (960 rows, K=768).
// cols 0..767 -> qb (*qscale, ld 768); cols 768..959 -> kvb (ld 192).
__global__ __launch_bounds__(256) void gemm_qkv(const u16* __restrict__ A, const u16* __restrict__ Bt,
    float* __restrict__ qb, float* __restrict__ kvb, float qscale)
{
    const int N = 960, K = DIM;
    int tid = threadIdx.x;
    int w = tid >> 6, lane = tid & 63;
    int m0 = blockIdx.y * 16;
    int n0 = blockIdx.x * 128 + w * 32;
    int row = lane & 15;
    int kg  = lane >> 4;
    const u16* arow = A + (size_t)(m0 + row) * K + kg * 8;
    int c0 = n0 + row;
    int c1 = n0 + 16 + row;
    const u16* bt0 = Bt + (size_t)min(c0, N - 1) * K + kg * 8;
    const u16* bt1 = Bt + (size_t)min(c1, N - 1) * K + kg * 8;
    f32x4 acc0 = {0.f, 0.f, 0.f, 0.f};
    f32x4 acc1 = {0.f, 0.f, 0.f, 0.f};
#pragma unroll 2
    for (int k0 = 0; k0 < K; k0 += 32) {
        short8v af = *(const short8v*)(arow + k0);
        short8v b0 = *(const short8v*)(bt0 + k0);
        short8v b1 = *(const short8v*)(bt1 + k0);
        acc0 = __builtin_amdgcn_mfma_f32_16x16x32_bf16(af, b0, acc0, 0, 0, 0);
        acc1 = __builtin_amdgcn_mfma_f32_16x16x32_bf16(af, b1, acc1, 0, 0, 0);
    }
#pragma unroll
    for (int r = 0; r < 4; r++) {
        int rw = m0 + kg * 4 + r;
        if (c0 < 768)      qb[(size_t)rw * 768 + c0] = acc0[r] * qscale;
        else if (c0 < 960) kvb[(size_t)rw * 192 + (c0 - 768)] = acc0[r];
        if (c1 < 768)      qb[(size_t)rw * 768 + c1] = acc1[r] * qscale;
        else if (c1 < 960) kvb[(size_t)rw * 192 + (c1 - 768)] = acc1[r];
    }
}

// ---------------------------------------------------------------- LayerNorm (bf16 out)
__global__ __launch_bounds__(256) void ln_k(const float* __restrict__ x, const float* __restrict__ g,
    const float* __restrict__ bb, u16* __restrict__ y)
{
    int row = blockIdx.x;
    const float* xr = x + (size_t)row * DIM;
    int tid = threadIdx.x;
    float v0 = xr[tid], v1 = xr[tid + 256], v2 = xr[tid + 512];
    __shared__ float red[4];
    float s = v0 + v1 + v2;
    for (int off = 32; off; off >>= 1) s += __shfl_down(s, off);
    if ((tid & 63) == 0) red[tid >> 6] = s;
    __syncthreads();
    float mean = (red[0] + red[1] + red[2] + red[3]) * (1.f / 768.f);
    __syncthreads();
    float d0 = v0 - mean, d1 = v1 - mean, d2 = v2 - mean;
    s = d0 * d0 + d1 * d1 + d2 * d2;
    for (int off = 32; off; off >>= 1) s += __shfl_down(s, off);
    if ((tid & 63) == 0) red[tid >> 6] = s;
    __syncthreads();
    float var = (red[0] + red[1] + red[2] + red[3]) * (1.f / 768.f);
    float rs = rsqrtf(var + 1e-5f);
    u16* yr = y + (size_t)row * DIM;
    yr[tid]       = f2bu(d0 * rs * g[tid]       + bb[tid]);
    yr[tid + 256] = f2bu(d1 * rs * g[tid + 256] + bb[tid + 256]);
    yr[tid + 512] = f2bu(d2 * rs * g[tid + 512] + bb[tid + 512]);
}

// Final LN over rows i>=10, f32 output (16,10,768)
__global__ __launch_bounds__(256) void lnf_k(const float* __restrict__ x, const float* __restrict__ g,
    const float* __restrict__ bb, float* __restrict__ out)
{
    int blk = blockIdx.x;
    int b = blk / 10, ii = blk - b * 10;
    int row = b * NSEQ + 10 + ii;
    const float* xr = x + (size_t)row * DIM;
    int tid = threadIdx.x;
    float v0 = xr[tid], v1 = xr[tid + 256], v2 = xr[tid + 512];
    __shared__ float red[4];
    float s = v0 + v1 + v2;
    for (int off = 32; off; off >>= 1) s += __shfl_down(s, off);
    if ((tid & 63) == 0) red[tid >> 6] = s;
    __syncthreads();
    float mean = (red[0] + red[1] + red[2] + red[3]) * (1.f / 768.f);
    __syncthreads();
    float d0 = v0 - mean, d1 = v1 - mean, d2 = v2 - mean;
    s = d0 * d0 + d1 * d1 + d2 * d2;
    for (int off = 32; off; off >>= 1) s += __shfl_down(s, off);
    if ((tid & 63) == 0) red[tid >> 6] = s;
    __syncthreads();
    float var = (red[0] + red[1] + red[2] + red[3]) * (1.f / 768.f);
    float rs = rsqrtf(var + 1e-5f);
    float* orow = out + ((size_t)(b * 10 + ii)) * DIM;
    orow[tid]       = d0 * rs * g[tid]       + bb[tid];
    orow[tid + 256] = d1 * rs * g[tid + 256] + bb[tid + 256];
    orow[tid + 512] = d2 * rs * g[tid + 512] + bb[tid + 512];
}

// ---------------------------------------------------------------- prefix rows
__global__ __launch_bounds__(256) void prefix_k(const float* __restrict__ p, float* __restrict__ t)
{
    int idx = blockIdx.x * 256 + threadIdx.x;
    if (idx < BB * 7680) {
        int b = idx / 7680;
        int r = idx - b * 7680;
        t[(size_t)b * (NSEQ * DIM) + 7680 + r] = p[r];
    }
}

// ---------------------------------------------------------------- local attention (ao bf16)
__global__ __launch_bounds__(256) void lattn_k(const float* __restrict__ q, const float* __restrict__ kv,
    u16* __restrict__ ao)
{
    int b = blockIdx.x, h = blockIdx.y;
    __shared__ float sims[NSEQ][NSEQ];
    __shared__ float probs[NSEQ][NSEQ];
    const float* qb = q + (size_t)b * NSEQ * DIM + h * DH;
    const float* kb = kv + (size_t)b * NSEQ * 192;
    int tid = threadIdx.x;
    for (int p = tid; p < NSEQ * NSEQ; p += 256) {
        int i = p / NSEQ, j = p - i * NSEQ;
        float s;
        if (j > i) s = -1.0e9f;
        else {
            s = 0.f;
            for (int d = 0; d < DH; d++) s = fmaf(qb[(size_t)i * DIM + d], kb[j * 192 + d], s);
        }
        sims[i][j] = s;
    }
    __syncthreads();
    if (tid < NSEQ) {
        int i = tid;
        float m = -1e30f;
        for (int j = 0; j < NSEQ; j++) m = fmaxf(m, sims[i][j]);
        float sum = 0.f;
        for (int j = 0; j < NSEQ; j++) { float e = expf(sims[i][j] - m); probs[i][j] = e; sum += e; }
        float inv = 1.f / sum;
        for (int j = 0; j < NSEQ; j++) probs[i][j] *= inv;
    }
    __syncthreads();
    for (int p = tid; p < NSEQ * DH; p += 256) {
        int i = p / DH, d = p - i * DH;
        float o = 0.f;
        for (int j = 0; j <= i; j++) o = fmaf(probs[i][j], kb[j * 192 + 96 + d], o);
        ao[((size_t)b * NSEQ + i) * DIM + h * DH + d] = f2bu(o);
    }
}

// ---------------------------------------------------------------- top-k helpers
__device__ __forceinline__ bool tk_better(float va, int ia, float vb, int ib) {
    return (va > vb) || (va == vb && ia < ib);
}

__device__ __forceinline__ void lds_fence() {
    asm volatile("s_waitcnt lgkmcnt(0)" ::: "memory");
    __builtin_amdgcn_sched_barrier(0);
}

// Exact top-32 of buf[0..cnt) by (value desc, idx asc). Bitonic-128 in regs.
__device__ void topk32(float* bv, int* bi, int cnt, int lane,
                       float& ov, int& oi, float& thr_out) {
    lds_fence();
    float v0 = (lane < cnt)      ? bv[lane]      : -3.0e38f;
    int   i0 = (lane < cnt)      ? bi[lane]      : 0x7fffffff;
    float v1 = (lane + 64 < cnt) ? bv[lane + 64] : -3.0e38f;
    int   i1 = (lane + 64 < cnt) ? bi[lane + 64] : 0x7fffffff;
    lds_fence();
#pragma unroll
    for (int k = 2; k <= 128; k <<= 1) {
#pragma unroll
        for (int j = 64; j >= 1; j >>= 1) {
            if (j >= k) continue;
            if (j == 64) {
                bool asc = ((lane & k) == 0);
                bool b01 = tk_better(v0, i0, v1, i1);
                if (b01 != asc) { float tv = v0; int ti = i0; v0 = v1; i0 = i1; v1 = tv; i1 = ti; }
            } else {
                {
                    float pv = __shfl_xor(v0, j); int pi = __shfl_xor(i0, j);
                    bool asc = ((lane & k) == 0);
                    bool first = ((lane & j) == 0);
                    bool mb = tk_better(v0, i0, pv, pi);
                    bool keep = first ? (mb == asc) : (mb != asc);
                    if (!keep) { v0 = pv; i0 = pi; }
                }
                {
                    float pv = __shfl_xor(v1, j); int pi = __shfl_xor(i1, j);
                    bool asc = (((lane + 64) & k) == 0);
                    bool first = ((lane & j) == 0);
                    bool mb = tk_better(v1, i1, pv, pi);
                    bool keep = first ? (mb == asc) : (mb != asc);
                    if (!keep) { v1 = pv; i1 = pi; }
                }
            }
        }
    }
    if (lane < 32) { bv[lane] = v0; bi[lane] = i0; }
    lds_fence();
    ov = v0; oi = i0;
    thr_out = __shfl(v0, 31);
}

// One 16-key pass: dot (quarter-split), 4-lane reduce, threshold/ballot append.
__device__ __forceinline__ void tk_pass(const float4 kr[6], const float4 qreg[5][6],
    float thrR[5], int cntR[5], float (*bufv)[CAP], int (*bufi)[CAP],
    int r0, int lane, int qt, int key)
{
    float a[5];
#pragma unroll
    for (int rr = 0; rr < 5; rr++) a[rr] = 0.f;
#pragma unroll
    for (int i = 0; i < 6; i++) {
        float4 kv = kr[i];
#pragma unroll
        for (int rr = 0; rr < 5; rr++) {
            float4 qv = qreg[rr][i];
            a[rr] = fmaf(qv.x, kv.x, a[rr]);
            a[rr] = fmaf(qv.y, kv.y, a[rr]);
            a[rr] = fmaf(qv.z, kv.z, a[rr]);
            a[rr] = fmaf(qv.w, kv.w, a[rr]);
        }
    }
#pragma unroll
    for (int rr = 0; rr < 5; rr++) {
        a[rr] += __shfl_xor(a[rr], 1);
        a[rr] += __shfl_xor(a[rr], 2);
    }
#pragma unroll
    for (int rr = 0; rr < 5; rr++) {
        bool cand = (qt == 0) && (a[rr] >= thrR[rr]);
        unsigned long long mask = __ballot(cand);
        int n = __popcll(mask);
        if (n) {
            int r = r0 + rr;
            if (cntR[rr] + n > CAP) {
                float dv; int di;
                topk32(&bufv[r][0], &bufi[r][0], cntR[rr], lane, dv, di, thrR[rr]);
                cntR[rr] = 32;
            }
            int pos = cntR[rr] + __popcll(mask & ((1ull << lane) - 1ull));
            if (cand) { bufv[r][pos] = a[rr]; bufi[r][pos] = key; }
            cntR[rr] += n;
        }
    }
}

// ---------------------------------------------------------------- mem top-k
// Block (c,h,b), 256 thr = 4 waves; wave w owns rows 5w..5w+4. Q in regs,
// k double-buffered in regs. 512 blocks (measured-best config).
__global__ __launch_bounds__(256, 2) void memtopk_k(const float* __restrict__ q, const float* __restrict__ memk,
    float* __restrict__ tkv, int* __restrict__ tki)
{
    __shared__ float bufv[NSEQ][CAP];
    __shared__ int   bufi[NSEQ][CAP];
    int c = blockIdx.x, h = blockIdx.y, b = blockIdx.z;
    int tid = threadIdx.x;
    int lane = tid & 63;
    int w = tid >> 6;
    int r0 = w * 5;
    int qt = lane & 3;
    int kk = lane >> 2;

    float4 qreg[5][6];
#pragma unroll
    for (int rr = 0; rr < 5; rr++) {
        const float4* qrow = (const float4*)(q + ((size_t)(b * NSEQ + r0 + rr)) * DIM + h * DH + qt * 24);
#pragma unroll
        for (int i = 0; i < 6; i++) qreg[rr][i] = qrow[i];
    }

    float thrR[5]; int cntR[5];
#pragma unroll
    for (int rr = 0; rr < 5; rr++) { thrR[rr] = -3.0e38f; cntR[rr] = 0; }

    const float* kbase = memk + (size_t)b * KMEM * DH;
    int k0 = c * CHUNK;

    float4 ka[6], kb2[6];
    {
        const float4* kp = (const float4*)(kbase + (size_t)(k0 + kk) * DH + qt * 24);
#pragma unroll
        for (int i = 0; i < 6; i++) ka[i] = kp[i];
    }
    for (int p = 0; p < CHUNK / 16; p += 2) {
        int key0 = k0 + p * 16 + kk;
        {
            const float4* kp = (const float4*)(kbase + (size_t)(key0 + 16) * DH + qt * 24);
#pragma unroll
            for (int i = 0; i < 6; i++) kb2[i] = kp[i];
        }
        tk_pass(ka, qreg, thrR, cntR, bufv, bufi, r0, lane, qt, key0);
        if (p + 2 < CHUNK / 16) {
            const float4* kp = (const float4*)(kbase + (size_t)(key0 + 32) * DH + qt * 24);
#pragma unroll
            for (int i = 0; i < 6; i++) ka[i] = kp[i];
        }
        tk_pass(kb2, qreg, thrR, cntR, bufv, bufi, r0, lane, qt, key0 + 16);
    }
#pragma unroll
    for (int rr = 0; rr < 5; rr++) {
        int r = r0 + rr;
        float ov; int oi; float dthr;
        topk32(&bufv[r][0], &bufi[r][0], cntR[rr], lane, ov, oi, dthr);
        if (lane < 32) {
            size_t base = ((((size_t)b * HEADS + h) * NSEQ + r) * NCHUNK + c) * 32;
            tkv[base + lane] = ov;
            tki[base + lane] = oi;
        }
    }
}

// ---------------------------------------------------------------- mem attention merge (per (i,h,b))
__global__ __launch_bounds__(64) void memattn_k(const float* __restrict__ q, const float* __restrict__ kv,
    const float* __restrict__ memv, const float* __restrict__ tkv, const int* __restrict__ tki,
    u16* __restrict__ ao)
{
    int i = blockIdx.x, h = blockIdx.y, b = blockIdx.z;
    __shared__ float cv[NCHUNK * 32];
    __shared__ int   ci[NCHUNK * 32];
    __shared__ float selv[32];
    __shared__ int   seli[32];
    __shared__ float ls[NSEQ];
    __shared__ float probs[52];
    int tid = threadIdx.x;
    size_t base = (((size_t)b * HEADS + h) * NSEQ + i) * (NCHUNK * 32);
#pragma unroll
    for (int s = 0; s < NCHUNK * 32 / 64; s++) {
        cv[tid + 64 * s] = tkv[base + tid + 64 * s];
        ci[tid + 64 * s] = tki[base + tid + 64 * s];
    }
    const float* qr = q + ((size_t)b * NSEQ + i) * DIM + h * DH;
    const float* kvb = kv + (size_t)b * NSEQ * 192;
    if (tid <= i) {
        float s = 0.f;
        for (int d = 0; d < DH; d++) s = fmaf(qr[d], kvb[tid * 192 + d], s);
        ls[tid] = s;
    }
    __syncthreads();
    for (int r = 0; r < 32; r++) {
        float bv = -3.0e38f; int bidx = 0x7fffffff; int bs = 0;
#pragma unroll
        for (int s = 0; s < NCHUNK * 32 / 64; s++) {
            float v = cv[tid + 64 * s]; int ix = ci[tid + 64 * s];
            if (tk_better(v, ix, bv, bidx)) { bv = v; bidx = ix; bs = tid + 64 * s; }
        }
        for (int off = 32; off; off >>= 1) {
            float ovv = __shfl_down(bv, off);
            int oii = __shfl_down(bidx, off);
            int oss = __shfl_down(bs, off);
            if (tk_better(ovv, oii, bv, bidx)) { bv = ovv; bidx = oii; bs = oss; }
        }
        if (tid == 0) { selv[r] = bv; seli[r] = bidx; cv[bs] = -3.0e38f; }
        __syncthreads();
    }
    if (tid == 0) {
        float m = -1e30f;
        for (int r = 0; r < 32; r++) m = fmaxf(m, selv[r]);
        for (int j = 0; j <= i; j++) m = fmaxf(m, ls[j]);
        float sum = 0.f;
        for (int r = 0; r < 32; r++) { float e = expf(selv[r] - m); probs[r] = e; sum += e; }
        for (int j = 0; j <= i; j++) { float e = expf(ls[j] - m); probs[32 + j] = e; sum += e; }
        float inv = 1.f / sum;
        for (int r = 0; r < 32 + i + 1; r++) probs[r] *= inv;
    }
    __syncthreads();
    const float* mvb = memv + (size_t)b * KMEM * DH;
    for (int d = tid; d < DH; d += 64) {
        float o = 0.f;
        for (int r = 0; r < 32; r++) o = fmaf(probs[r], mvb[(size_t)seli[r] * DH + d], o);
        for (int j = 0; j <= i; j++) o = fmaf(probs[32 + j], kvb[j * 192 + 96 + d], o);
        ao[((size_t)b * NSEQ + i) * DIM + h * DH + d] = f2bu(o);
    }
}

// ---------------------------------------------------------------- host
extern "C" void kernel_launch(void* const* d_in, const int* in_sizes, int n_in,
                              void* d_out, int out_size, void* d_ws, size_t ws_size,
                              hipStream_t stream) {
    const float* x            = (const float*)d_in[0];
    const float* linear_w     = (const float*)d_in[1];
    const float* linear_b     = (const float*)d_in[2];
    const float* prefix_const = (const float*)d_in[3];
    const float* ln1_g        = (const float*)d_in[4];
    const float* ln1_b        = (const float*)d_in[5];
    const float* wq           = (const float*)d_in[6];
    const float* wkv          = (const float*)d_in[7];
    const float* wo           = (const float*)d_in[8];
    const float* ln2_g        = (const float*)d_in[9];
    const float* ln2_b        = (const float*)d_in[10];
    const float* w1           = (const float*)d_in[11];
    const float* b1           = (const float*)d_in[12];
    const float* w2           = (const float*)d_in[13];
    const float* b2           = (const float*)d_in[14];
    const float* lnf_g        = (const float*)d_in[15];
    const float* lnf_b        = (const float*)d_in[16];
    const float* mem_k        = (const float*)d_in[17];
    const float* mem_v        = (const float*)d_in[18];

    float* ws = (float*)d_ws;
    float* t    = ws;                     // 320*768 f32
    u16*   yb   = (u16*)(ws + 245760);    // 320*768 bf16
    float* qb   = ws + 491520;            // 320*768 f32
    float* kvb  = ws + 737280;            // 320*192 f32
    u16*   aob  = (u16*)(ws + 798720);    // 320*768 bf16
    u16*   h1b  = (u16*)(ws + 1044480);   // 320*3072 bf16
    float* tkv  = ws + 2027520;           // 16*8*20*4*32 = 327680
    int*   tki  = (int*)(ws + 2355200);   // 327680
    u16*   wt   = (u16*)(ws + 2682880);   // weight slots (bf16)
    float* out  = (float*)d_out;

    const size_t LAYER_WT = 6045696;      // shorts per layer slot
    // all-8-layer conversion needs 2682880 + 8*3022848 + 2560 f32 words
    const int all8 = (ws_size >= (size_t)(2682880 + 8 * 3022848 + 2560) * 4) ? 1 : 0;
    u16* xb = (u16*)(ws + (all8 ? (2682880 + 8 * 3022848) : (2682880 + 3022848)));

    const float qscale = 0.10206207261596577f; // 96^-0.5
    const size_t WOT = 737280, W1T = 1327104, W2T = 3686400;

    // x -> bf16; linear_w^T -> wt slot 0 (overwritten later by layer weights)
    conv_k<<<40, 256, 0, stream>>>(x, xb, 16 * 640);
    tconv_k<<<4800, 256, 0, stream>>>(linear_w, wt, 640, 7680);
    gemm_bt<float><<<dim3(60, 1), 256, 0, stream>>>(xb, wt, linear_b, nullptr, t,
                                                    16, 7680, 640, 640, 15360, 1.f, 0);
    prefix_k<<<dim3(480), 256, 0, stream>>>(prefix_const, t);

    if (all8)
        wconv5L_k<<<dim3(5904, 8), 256, 0, stream>>>(wq, wkv, wo, w1, w2, wt, LAYER_WT);

    for (int l = 0; l < 8; l++) {
        u16* wtl = wt + (all8 ? (size_t)l * LAYER_WT : 0);
        if (!all8)
            wconv5L_k<<<dim3(5904, 1), 256, 0, stream>>>(wq + (size_t)l * 589824, wkv + (size_t)l * 147456,
                                                         wo + (size_t)l * 589824, w1 + (size_t)l * 2359296,
                                                         w2 + (size_t)l * 2359296, wtl, 0);
        ln_k<<<320, 256, 0, stream>>>(t, ln1_g + (size_t)l * DIM, ln1_b + (size_t)l * DIM, yb);
        gemm_qkv<<<dim3(8, 20), 256, 0, stream>>>(yb, wtl, qb, kvb, qscale);
        if (l == 4 || l == 5) {
            memtopk_k<<<dim3(NCHUNK, HEADS, BB), 256, 0, stream>>>(qb, mem_k, tkv, tki);
            memattn_k<<<dim3(NSEQ, HEADS, BB), 64, 0, stream>>>(qb, kvb, mem_v, tkv, tki, aob);
        } else {
            lattn_k<<<dim3(BB, HEADS), 256, 0, stream>>>(qb, kvb, aob);
        }
        gemm_bt<float><<<dim3(6, 20), 256, 0, stream>>>(aob, wtl + WOT, nullptr, t, t,
                                                        320, 768, 768, 768, 768, 1.f, 0);
        ln_k<<<320, 256, 0, stream>>>(t, ln2_g + (size_t)l * DIM, ln2_b + (size_t)l * DIM, yb);
        gemm_bt<u16><<<dim3(24, 20), 256, 0, stream>>>(yb, wtl + W1T, b1 + (size_t)l * FF, nullptr, h1b,
                                                       320, 3072, 768, 768, 3072, 1.f, 1);
        gemm_bt<float><<<dim3(6, 20), 256, 0, stream>>>(h1b, wtl + W2T, b2 + (size_t)l * DIM, t, t,
                                                        320, 768, 3072, 3072, 768, 1.f, 0);
    }
    lnf_k<<<160, 256, 0, stream>>>(t, lnf_g, lnf_b, out);
}